// Round 11
// baseline (879.133 us; speedup 1.0000x reference)
//
#include <hip/hip_runtime.h>
#include <hip/hip_bf16.h>

// AdaptiveEdgeGAT: N=50000, E=800000, IN=OUT=128, EDGE=64, H=4, D=32
// CSR (sort-by-dst) + gather-based segmented reductions.
// R1: wave-per-node node_agg. R2: edge-GEMM on MFMA. R4: logits fused in.
// R5: rank-from-atomic hist + atomic-free permute. R6: k_fuse on MFMA.
// R7: k_proj on MFMA. R8: (256,4)/64-VGPR + LDS f_src row cache.
// R9/R10: fat-kernel overlaps + merged node_agg; reg-prefetch reverted (spill).
// R11: node_agg occupancy via LDS: CAPR 32->24 (39.9->31.2 KB/block) +
//      launch_bounds(256,5) -> 5 blocks/CU (was LDS-capped at 4). VGPR cap at
//      5 waves/SIMD is ~102 >= 64 so no allocator squeeze (R7 lesson).
//      P(deg>24)~2% re-gathers L2-warm. Single-lever round.

#define N_NODES 50000
#define N_EDGES 800000
#define IN_DIM 128
#define OUT_DIM 128
#define EDGE_DIM 64
#define HEADS 4
#define HEAD_DIM 32
#define NEG_SLOPE 0.2f

typedef __hip_bfloat16 bf16;
typedef unsigned short u16;
typedef unsigned int u32;
typedef unsigned long long u64;
typedef __attribute__((ext_vector_type(8))) short bf16x8;
typedef __attribute__((ext_vector_type(4))) float f32x4;

// canonical f32 weight-block offsets (floats)
#define OFF_WSRC 0
#define OFF_BSRC 16384
#define OFF_WDST 16512
#define OFF_BDST 32896
#define OFF_ATTN 33024
#define OFF_WEDGE 33152
#define OFF_BEDGE 41344
#define OFF_WGATE 41472
#define OFF_BGATE 74240
#define OFF_WOUT 74368
#define OFF_BOUT 90752
#define OFF_WEDGE_T 90880   // transposed W_edge: [col][k] = [128][64] (f32, cold path)
#define OFF_WFRAG 99072     // bf16 B-fragments of W_edge^T: 4096 u32 words (16KB)
#define OFF_WFG 103168      // bf16 B-fragments of W_gate: [ct8][tt8][64][4w] = 16384
#define OFF_WFO_HI 119552   // bf16 B-fragments of W_out (hi): [ct8][tt4][64][4w] = 8192
#define OFF_WFO_LO 127744   // bf16 B-fragments of W_out (lo residual): 8192
#define OFF_WFS_HI 135936   // W_src hi fragments: 8192
#define OFF_WFS_LO 144128   // W_src lo fragments: 8192
#define OFF_WFD_HI 152320   // W_dst hi fragments: 8192
#define OFF_WFD_LO 160512   // W_dst lo fragments: 8192
#define W_TOTAL 168704

#define WCONV_BLOCKS 659    // W_TOTAL/256
#define HIST_BLOCKS 3125    // ceil(E/256)
#define PROJ_BLOCKS 782     // ceil(N/64)

__device__ __forceinline__ float b2f_raw(u16 v) {
    return __uint_as_float(((u32)v) << 16);
}
__device__ __forceinline__ float b2f(bf16 v) { return __bfloat162float(v); }
__device__ __forceinline__ float loadin(const void* p, long i, int isbf) {
    return isbf ? b2f_raw(((const u16*)p)[i]) : ((const float*)p)[i];
}
__device__ __forceinline__ float lo16(u32 v) { return __uint_as_float(v << 16); }
__device__ __forceinline__ float hi16(u32 v) { return __uint_as_float(v & 0xFFFF0000u); }
__device__ __forceinline__ u16 f2b_bits(float x) {
    bf16 t = __float2bfloat16(x);
    return *reinterpret_cast<u16*>(&t);
}
// per-col-pair logit partial: leaky_relu(fs + fd) dot attn_w (2 cols of this lane)
__device__ __forceinline__ float logit_part(u32 v, float fdlo, float fdhi, float2 awc) {
    float x0 = lo16(v) + fdlo; x0 = x0 > 0.f ? x0 : NEG_SLOPE * x0;
    float x1 = hi16(v) + fdhi; x1 = x1 > 0.f ? x1 : NEG_SLOPE * x1;
    return x0 * awc.x + x1 * awc.y;
}
// sum across the 16-lane head group
__device__ __forceinline__ float red16(float r) {
    r += __shfl_xor(r, 1); r += __shfl_xor(r, 2);
    r += __shfl_xor(r, 4); r += __shfl_xor(r, 8);
    return r;
}

// ---------- init: dtype detect (block 0) + zero degree counters (all blocks) ----------
__global__ __launch_bounds__(256) void k_init(const void* node, int* flag, int* __restrict__ deg) {
    int i = blockIdx.x * 256 + threadIdx.x;
    if (i < N_NODES) deg[i] = 0;
    if (blockIdx.x == 0) {
        __shared__ int cnt[256];
        int c = 0;
        for (int j = threadIdx.x; j < 8192; j += 256) {
            float v = b2f_raw(((const u16*)node)[j]);
            float a = fabsf(v);
            if ((a >= 1e-4f && a <= 50.f) || v == 0.f) c++;
        }
        cnt[threadIdx.x] = c;
        __syncthreads();
        for (int s = 128; s > 0; s >>= 1) {
            if (threadIdx.x < s) cnt[threadIdx.x] += cnt[threadIdx.x + s];
            __syncthreads();
        }
        if (threadIdx.x == 0) flag[0] = (cnt[0] >= (8192 * 85) / 100) ? 1 : 0;
    }
}

// ---------- fused: weight canonicalization (blocks 0..658) || degree histogram ----------
__global__ __launch_bounds__(256) void k_prep(const void* Wsrc, const void* bsrc,
                                              const void* Wdst, const void* bdst,
                                              const void* attn, const void* Wedge, const void* bedge,
                                              const void* Wgate, const void* bgate,
                                              const void* Wout, const void* bout,
                                              float* w, const int* flag,
                                              const int* __restrict__ dst, int* __restrict__ deg,
                                              int* __restrict__ rank) {
    if (blockIdx.x >= WCONV_BLOCKS) {
        int e = (blockIdx.x - WCONV_BLOCKS) * 256 + threadIdx.x;
        if (e < N_EDGES) rank[e] = atomicAdd(&deg[dst[e]], 1);
        return;
    }
    int i = blockIdx.x * 256 + threadIdx.x;
    if (i >= W_TOTAL) return;
    int f = flag[0];
    const void* p; long off;
    if (i < OFF_BSRC)         { p = Wsrc;  off = i - OFF_WSRC; }
    else if (i < OFF_WDST)    { p = bsrc;  off = i - OFF_BSRC; }
    else if (i < OFF_BDST)    { p = Wdst;  off = i - OFF_WDST; }
    else if (i < OFF_ATTN)    { p = bdst;  off = i - OFF_BDST; }
    else if (i < OFF_WEDGE)   { p = attn;  off = i - OFF_ATTN; }
    else if (i < OFF_BEDGE)   { p = Wedge; off = i - OFF_WEDGE; }
    else if (i < OFF_WGATE)   { p = bedge; off = i - OFF_BEDGE; }
    else if (i < OFF_BGATE)   { p = Wgate; off = i - OFF_WGATE; }
    else if (i < OFF_WOUT)    { p = bgate; off = i - OFF_BGATE; }
    else if (i < OFF_BOUT)    { p = Wout;  off = i - OFF_WOUT; }
    else if (i < OFF_WEDGE_T) { p = bout;  off = i - OFF_BOUT; }
    else if (i < OFF_WFRAG) { // transposed W_edge: wt[col*64+k] = W_edge[k*128+col]
        int idx = i - OFF_WEDGE_T;
        int col = idx >> 6, k = idx & 63;
        w[i] = loadin(Wedge, (long)k * OUT_DIM + col, f);
        return;
    } else if (i < OFF_WFG) {
        // W_edge fragments: wdx = mt*512 + tt*256 + l*4 + s/2 (k in 0..63)
        int wdx = i - OFF_WFRAG;
        int sp = (wdx & 3) * 2;
        int l = (wdx >> 2) & 63;
        int tt = (wdx >> 8) & 1;
        int mt = wdx >> 9;
        int k0 = tt * 32 + ((l >> 4) << 3);
        int col = mt * 16 + (l & 15);
        float v0 = loadin(Wedge, (long)(k0 + sp) * OUT_DIM + col, f);
        float v1 = loadin(Wedge, (long)(k0 + sp + 1) * OUT_DIM + col, f);
        *(u32*)&w[i] = (u32)f2b_bits(v0) | ((u32)f2b_bits(v1) << 16);
        return;
    } else if (i < OFF_WFO_HI) {
        // W_gate fragments: wdx = ct*2048 + tt*256 + l*4 + s/2 (k in 0..255)
        int wdx = i - OFF_WFG;
        int sp = (wdx & 3) * 2;
        int l = (wdx >> 2) & 63;
        int tt = (wdx >> 8) & 7;
        int ct = wdx >> 11;
        int k0 = tt * 32 + ((l >> 4) << 3);
        int c = ct * 16 + (l & 15);
        float v0 = loadin(Wgate, (long)(k0 + sp) * OUT_DIM + c, f);
        float v1 = loadin(Wgate, (long)(k0 + sp + 1) * OUT_DIM + c, f);
        *(u32*)&w[i] = (u32)f2b_bits(v0) | ((u32)f2b_bits(v1) << 16);
        return;
    } else {
        // 128-k matrices (W_out/W_src/W_dst, hi or lo): wdx = ct*1024 + tt*256 + l*4 + s/2
        const void* M; int base; int wantlo;
        if (i < OFF_WFO_LO)      { M = Wout; base = OFF_WFO_HI; wantlo = 0; }
        else if (i < OFF_WFS_HI) { M = Wout; base = OFF_WFO_LO; wantlo = 1; }
        else if (i < OFF_WFS_LO) { M = Wsrc; base = OFF_WFS_HI; wantlo = 0; }
        else if (i < OFF_WFD_HI) { M = Wsrc; base = OFF_WFS_LO; wantlo = 1; }
        else if (i < OFF_WFD_LO) { M = Wdst; base = OFF_WFD_HI; wantlo = 0; }
        else                     { M = Wdst; base = OFF_WFD_LO; wantlo = 1; }
        int wdx = i - base;
        int sp = (wdx & 3) * 2;
        int l = (wdx >> 2) & 63;
        int tt = (wdx >> 8) & 3;
        int ct = wdx >> 10;
        int k0 = tt * 32 + ((l >> 4) << 3);
        int c = ct * 16 + (l & 15);
        float v0 = loadin(M, (long)(k0 + sp) * OUT_DIM + c, f);
        float v1 = loadin(M, (long)(k0 + sp + 1) * OUT_DIM + c, f);
        if (wantlo) {
            v0 = v0 - b2f_raw(f2b_bits(v0));
            v1 = v1 - b2f_raw(f2b_bits(v1));
        }
        *(u32*)&w[i] = (u32)f2b_bits(v0) | ((u32)f2b_bits(v1) << 16);
        return;
    }
    w[i] = loadin(p, off, f);
}

// ---------- exclusive prefix sum: thread-coarsened, 22 barriers total ----------
#define SCAN_CHUNK 49   // 49*1024 = 50176 >= N_NODES
__global__ __launch_bounds__(1024) void k_scan(const int* __restrict__ deg,
                                               int* __restrict__ rowptr) {
    __shared__ int part[1024];
    int tid = threadIdx.x;
    int base = tid * SCAN_CHUNK;
    int s = 0;
    for (int j = 0; j < SCAN_CHUNK; j++) {
        int i = base + j;
        if (i < N_NODES) s += deg[i];
    }
    part[tid] = s;
    __syncthreads();
    for (int st = 1; st < 1024; st <<= 1) {
        int v = (tid >= st) ? part[tid - st] : 0;
        __syncthreads();
        part[tid] += v;
        __syncthreads();
    }
    int run = (tid == 0) ? 0 : part[tid - 1];
    for (int j = 0; j < SCAN_CHUNK; j++) {
        int i = base + j;
        if (i < N_NODES) {
            rowptr[i] = run;
            run += deg[i];
        }
    }
    if (N_NODES >= base && N_NODES < base + SCAN_CHUNK) rowptr[N_NODES] = run;
}

// ---------- fused: node projections on MFMA (blocks 0..781) || edge permute ----------
#define PROJ_PAD 134
__global__ __launch_bounds__(256, 4) void k_pp(const void* __restrict__ node,
                                              const float* __restrict__ w, const int* __restrict__ flag,
                                              bf16* __restrict__ f_src, bf16* __restrict__ f_dst,
                                              const int* __restrict__ dst,
                                              const int* __restrict__ rowptr,
                                              const int* __restrict__ rank,
                                              int* __restrict__ perm) {
    if (blockIdx.x >= PROJ_BLOCKS) {
        int e = (blockIdx.x - PROJ_BLOCKS) * 256 + threadIdx.x;
        if (e < N_EDGES) perm[rowptr[dst[e]] + rank[e]] = e;
        return;
    }
    __shared__ float s_t[4][16][PROJ_PAD];
    const int wv = threadIdx.x >> 6;
    const int lane = threadIdx.x & 63;
    const int g = lane >> 4, j16 = lane & 15;
    const int isbf = flag[0];
    const long row0 = (long)blockIdx.x * 64 + wv * 16;
    if (row0 >= N_NODES) return;
    float (*t32)[PROJ_PAD] = s_t[wv];
    long jr = row0 + j16; if (jr >= N_NODES) jr = N_NODES - 1;

    uint4 ah[4], al[4];
    if (isbf) {
        const uint4* np = (const uint4*)node;
#pragma unroll
        for (int tt = 0; tt < 4; tt++) ah[tt] = np[jr * 16 + tt * 4 + g];
    } else {
        const float4* np = (const float4*)node;
#pragma unroll
        for (int tt = 0; tt < 4; tt++) {
            float4 x0 = np[jr * 32 + tt * 8 + g * 2];
            float4 x1 = np[jr * 32 + tt * 8 + g * 2 + 1];
            float xv[8] = {x0.x, x0.y, x0.z, x0.w, x1.x, x1.y, x1.z, x1.w};
            u32 hw[4], lw[4];
#pragma unroll
            for (int s2 = 0; s2 < 4; s2++) {
                u16 h0 = f2b_bits(xv[s2 * 2]), h1 = f2b_bits(xv[s2 * 2 + 1]);
                float r0 = xv[s2 * 2] - b2f_raw(h0);
                float r1 = xv[s2 * 2 + 1] - b2f_raw(h1);
                hw[s2] = (u32)h0 | ((u32)h1 << 16);
                lw[s2] = (u32)f2b_bits(r0) | ((u32)f2b_bits(r1) << 16);
            }
            ah[tt] = make_uint4(hw[0], hw[1], hw[2], hw[3]);
            al[tt] = make_uint4(lw[0], lw[1], lw[2], lw[3]);
        }
    }

    const bf16x8* wsh = (const bf16x8*)(w + OFF_WFS_HI);
    const bf16x8* wsl = (const bf16x8*)(w + OFF_WFS_LO);
    const bf16x8* wdh = (const bf16x8*)(w + OFF_WFD_HI);
    const bf16x8* wdl = (const bf16x8*)(w + OFF_WFD_LO);

    // ---- f_src = x @ W_src + b ----
#pragma unroll
    for (int ct = 0; ct < 8; ct++) {
        float bs = w[OFF_BSRC + ct * 16 + j16];
        f32x4 c = {bs, bs, bs, bs};
#pragma unroll
        for (int tt = 0; tt < 4; tt++) {
            bf16x8 a = *reinterpret_cast<bf16x8*>(&ah[tt]);
            c = __builtin_amdgcn_mfma_f32_16x16x32_bf16(a, wsh[(ct * 4 + tt) * 64 + lane], c, 0, 0, 0);
            c = __builtin_amdgcn_mfma_f32_16x16x32_bf16(a, wsl[(ct * 4 + tt) * 64 + lane], c, 0, 0, 0);
        }
        if (!isbf) {
#pragma unroll
            for (int tt = 0; tt < 4; tt++)
                c = __builtin_amdgcn_mfma_f32_16x16x32_bf16(*reinterpret_cast<bf16x8*>(&al[tt]),
                                                            wsh[(ct * 4 + tt) * 64 + lane], c, 0, 0, 0);
        }
#pragma unroll
        for (int r = 0; r < 4; r++) t32[g * 4 + r][ct * 16 + j16] = c[r];
    }
    for (int it = 0; it < 16; it++) {
        long rr = row0 + it;
        if (rr >= N_NODES) break;
        ((u32*)f_src)[rr * 64 + lane] =
            (u32)f2b_bits(t32[it][lane * 2]) | ((u32)f2b_bits(t32[it][lane * 2 + 1]) << 16);
    }

    // ---- f_dst = x @ W_dst + b ----
#pragma unroll
    for (int ct = 0; ct < 8; ct++) {
        float bd = w[OFF_BDST + ct * 16 + j16];
        f32x4 c = {bd, bd, bd, bd};
#pragma unroll
        for (int tt = 0; tt < 4; tt++) {
            bf16x8 a = *reinterpret_cast<bf16x8*>(&ah[tt]);
            c = __builtin_amdgcn_mfma_f32_16x16x32_bf16(a, wdh[(ct * 4 + tt) * 64 + lane], c, 0, 0, 0);
            c = __builtin_amdgcn_mfma_f32_16x16x32_bf16(a, wdl[(ct * 4 + tt) * 64 + lane], c, 0, 0, 0);
        }
        if (!isbf) {
#pragma unroll
            for (int tt = 0; tt < 4; tt++)
                c = __builtin_amdgcn_mfma_f32_16x16x32_bf16(*reinterpret_cast<bf16x8*>(&al[tt]),
                                                            wdh[(ct * 4 + tt) * 64 + lane], c, 0, 0, 0);
        }
#pragma unroll
        for (int r = 0; r < 4; r++) t32[g * 4 + r][ct * 16 + j16] = c[r];
    }
    for (int it = 0; it < 16; it++) {
        long rr = row0 + it;
        if (rr >= N_NODES) break;
        ((u32*)f_dst)[rr * 64 + lane] =
            (u32)f2b_bits(t32[it][lane * 2]) | ((u32)f2b_bits(t32[it][lane * 2 + 1]) << 16);
    }
}

// ---------- per-node aggregation: wave-per-node, fused logits+softmax+agg ----------
// All LDS wave-private -> zero barriers. Single dispatch. R11: CAPR 24 + 5 blocks/CU.
#define CAPR 24   // cached f_src rows per node (P(deg>24)~2% re-gathers L2-warm)
__global__ __launch_bounds__(256, 5) void k_node_agg(const int* __restrict__ rowptr,
                                                  const int* __restrict__ perm,
                                                  const int* __restrict__ src,
                                                  const bf16* __restrict__ f_src,
                                                  const bf16* __restrict__ f_dst,
                                                  const void* __restrict__ edge_feat,
                                                  const float* __restrict__ w, const int* __restrict__ flag,
                                                  bf16* __restrict__ h_node, bf16* __restrict__ edge_max,
                                                  bf16* __restrict__ out_a_b, float* __restrict__ out_a_f) {
    __shared__ int s_esrc[4][64];
    __shared__ __align__(16) float s_a[4][64][4];
    __shared__ __align__(16) float s_vmax[4][128];
    __shared__ u32 s_xs[4][CAPR][64];   // cached f_src rows (u32 = 2 bf16 cols/lane)

    const int wv = threadIdx.x >> 6;
    const int lane = threadIdx.x & 63;
    const int n = blockIdx.x * 4 + wv;
    const int isbf = flag[0];
    const int r0 = rowptr[n], r1 = rowptr[n + 1];
    const int deg = r1 - r0;

    int* esrc = s_esrc[wv];
    float (*aA)[4] = s_a[wv];
    float* vm = s_vmax[wv];
    u32 (*xs)[64] = s_xs[wv];

    const u32* fs32 = (const u32*)f_src;
    const int g = lane >> 4;          // head group of this lane's column pair
    const int dm = deg < 64 ? deg : 64;

    // ---- Phase 1: per-lane edge metadata ----
    int e0 = 0, sv = 0;
    if (lane < deg) {
        e0 = perm[r0 + lane];
        sv = src[e0];
        esrc[lane] = sv;
    }

    // ---- Phase L: fused GATv2 logits (+ row cache fill) ----
    u32 fdw = ((const u32*)f_dst)[(long)n * 64 + lane];
    const float fdlo = lo16(fdw), fdhi = hi16(fdw);
    const float2 awc = *(const float2*)&w[OFF_ATTN + lane * 2];
    {
        int j = 0;
        for (; j + 4 <= dm; j += 4) {
            int sA = __shfl(sv, j), sB = __shfl(sv, j + 1);
            int sC = __shfl(sv, j + 2), sD = __shfl(sv, j + 3);
            u32 vA = fs32[(long)sA * 64 + lane];
            u32 vB = fs32[(long)sB * 64 + lane];
            u32 vC = fs32[(long)sC * 64 + lane];
            u32 vD = fs32[(long)sD * 64 + lane];
            if (j + 3 < CAPR) {
                xs[j][lane] = vA; xs[j + 1][lane] = vB;
                xs[j + 2][lane] = vC; xs[j + 3][lane] = vD;
            }
            float rA = red16(logit_part(vA, fdlo, fdhi, awc));
            float rB = red16(logit_part(vB, fdlo, fdhi, awc));
            float rC = red16(logit_part(vC, fdlo, fdhi, awc));
            float rD = red16(logit_part(vD, fdlo, fdhi, awc));
            if ((lane & 15) == 0) {
                aA[j][g] = rA; aA[j + 1][g] = rB;
                aA[j + 2][g] = rC; aA[j + 3][g] = rD;
            }
        }
        for (; j < dm; j++) {
            int sA = __shfl(sv, j);
            u32 vA = fs32[(long)sA * 64 + lane];
            if (j < CAPR) xs[j][lane] = vA;
            float rA = red16(logit_part(vA, fdlo, fdhi, awc));
            if ((lane & 15) == 0) aA[j][g] = rA;
        }
    }

    // ---- Phase 2: softmax in registers (lane j owns edge j) ----
    float l0 = -3.0e38f, l1 = -3.0e38f, l2 = -3.0e38f, l3 = -3.0e38f;
    if (lane < deg) {
        float4 lv = *(float4*)aA[lane];
        l0 = lv.x; l1 = lv.y; l2 = lv.z; l3 = lv.w;
    }
    float m0 = l0, m1 = l1, m2 = l2, m3 = l3;
#pragma unroll
    for (int s = 1; s < 64; s <<= 1) {
        m0 = fmaxf(m0, __shfl_xor(m0, s));
        m1 = fmaxf(m1, __shfl_xor(m1, s));
        m2 = fmaxf(m2, __shfl_xor(m2, s));
        m3 = fmaxf(m3, __shfl_xor(m3, s));
    }
    for (int jj = 64; jj < deg; jj++) {   // cold: deg > 64 — cooperative logit, max
        int e = perm[r0 + jj];
        int s0 = src[e];
        u32 v = fs32[(long)s0 * 64 + lane];
        float red = red16(logit_part(v, fdlo, fdhi, awc));
        float q0 = __shfl(red, 0), q1 = __shfl(red, 16);
        float q2 = __shfl(red, 32), q3 = __shfl(red, 48);
        m0 = fmaxf(m0, q0); m1 = fmaxf(m1, q1);
        m2 = fmaxf(m2, q2); m3 = fmaxf(m3, q3);
    }
    float p0 = 0.f, p1 = 0.f, p2 = 0.f, p3 = 0.f;
    if (lane < deg) {
        p0 = __expf(l0 - m0); p1 = __expf(l1 - m1);
        p2 = __expf(l2 - m2); p3 = __expf(l3 - m3);
    }
    float t0 = p0, t1 = p1, t2 = p2, t3 = p3;
#pragma unroll
    for (int s = 1; s < 64; s <<= 1) {
        t0 += __shfl_xor(t0, s);
        t1 += __shfl_xor(t1, s);
        t2 += __shfl_xor(t2, s);
        t3 += __shfl_xor(t3, s);
    }
    for (int jj = 64; jj < deg; jj++) {   // cold: sum of overflow exps (uniform)
        int e = perm[r0 + jj];
        int s0 = src[e];
        u32 v = fs32[(long)s0 * 64 + lane];
        float red = red16(logit_part(v, fdlo, fdhi, awc));
        t0 += __expf(__shfl(red, 0) - m0);
        t1 += __expf(__shfl(red, 16) - m1);
        t2 += __expf(__shfl(red, 32) - m2);
        t3 += __expf(__shfl(red, 48) - m3);
    }
    const float i0 = 1.f / fmaxf(t0, 1e-9f);
    const float i1 = 1.f / fmaxf(t1, 1e-9f);
    const float i2 = 1.f / fmaxf(t2, 1e-9f);
    const float i3 = 1.f / fmaxf(t3, 1e-9f);
    if (lane < deg) {
        float a0 = p0 * i0, a1 = p1 * i1, a2 = p2 * i2, a3 = p3 * i3;
        *(float4*)aA[lane] = make_float4(a0, a1, a2, a3);
        if (isbf) {
            u64 pk = (u64)f2b_bits(a0) | ((u64)f2b_bits(a1) << 16)
                   | ((u64)f2b_bits(a2) << 32) | ((u64)f2b_bits(a3) << 48);
            ((u64*)out_a_b)[e0] = pk;
        } else {
            ((float4*)out_a_f)[e0] = make_float4(a0, a1, a2, a3);
        }
    }

    // ---- Phase 3a: message accumulate — cached rows from LDS, rest from global ----
    const int hsel = g;
    float acc0 = 0.f, acc1 = 0.f;
    const int capn = dm < CAPR ? dm : CAPR;
    int j = 0;
    for (; j + 4 <= capn; j += 4) {
        float a0 = aA[j][hsel], a1 = aA[j + 1][hsel];
        float a2 = aA[j + 2][hsel], a3 = aA[j + 3][hsel];
        u32 v0 = xs[j][lane];
        u32 v1 = xs[j + 1][lane];
        u32 v2 = xs[j + 2][lane];
        u32 v3 = xs[j + 3][lane];
        acc0 += lo16(v0) * a0 + lo16(v1) * a1 + lo16(v2) * a2 + lo16(v3) * a3;
        acc1 += hi16(v0) * a0 + hi16(v1) * a1 + hi16(v2) * a2 + hi16(v3) * a3;
    }
    for (; j < capn; j++) {
        float a0 = aA[j][hsel];
        u32 v0 = xs[j][lane];
        acc0 += lo16(v0) * a0;
        acc1 += hi16(v0) * a0;
    }
    for (; j < dm; j++) {   // deg in (CAPR,64]: re-gather (L2-warm)
        int s0 = esrc[j];
        float a0 = aA[j][hsel];
        u32 v0 = fs32[(long)s0 * 64 + lane];
        acc0 += lo16(v0) * a0;
        acc1 += hi16(v0) * a0;
    }
    if (deg > 64) {   // cold: cooperative logit -> a -> out_a + message
        float mh = (hsel & 2) ? ((hsel & 1) ? m3 : m2) : ((hsel & 1) ? m1 : m0);
        float ih = (hsel & 2) ? ((hsel & 1) ? i3 : i2) : ((hsel & 1) ? i1 : i0);
        for (int jj = 64; jj < deg; jj++) {
            int e = perm[r0 + jj];
            int s0 = src[e];
            u32 v = fs32[(long)s0 * 64 + lane];
            float red = red16(logit_part(v, fdlo, fdhi, awc));
            float q0 = __shfl(red, 0), q1 = __shfl(red, 16);
            float q2 = __shfl(red, 32), q3 = __shfl(red, 48);
            float a0 = __expf(q0 - m0) * i0, a1 = __expf(q1 - m1) * i1;
            float a2 = __expf(q2 - m2) * i2, a3 = __expf(q3 - m3) * i3;
            if (lane == 0) {
                if (isbf) {
                    u64 pk = (u64)f2b_bits(a0) | ((u64)f2b_bits(a1) << 16)
                           | ((u64)f2b_bits(a2) << 32) | ((u64)f2b_bits(a3) << 48);
                    ((u64*)out_a_b)[e] = pk;
                } else {
                    ((float4*)out_a_f)[e] = make_float4(a0, a1, a2, a3);
                }
            }
            float qh = (hsel & 2) ? ((hsel & 1) ? q3 : q2) : ((hsel & 1) ? q1 : q0);
            float ah = __expf(qh - mh) * ih;
            acc0 += lo16(v) * ah;
            acc1 += hi16(v) * ah;
        }
    }
    ((u32*)h_node)[n * 64 + lane] =
        (u32)f2b_bits(acc0) | ((u32)f2b_bits(acc1) << 16);

    // ---- Phase 3b: edge encoder GEMM on MFMA + column max ----
    if (deg == 0) {
        ((u32*)edge_max)[(long)n * 64 + lane] = 0u;
        return;
    }
    {
        const bf16x8* wfb = (const bf16x8*)(w + OFF_WFRAG);
        const int ntiles = deg >= 64 ? 4 : ((deg + 15) >> 4);
        for (int nt = 0; nt < ntiles; nt++) {
            const int je = nt * 16 + (lane & 15);
            const int ej = __shfl(e0, je);      // e0 defaults 0 for pad lanes (masked below)
            bf16x8 bf0, bf1;
            if (isbf) {
                const uint4* ef = (const uint4*)edge_feat;
                uint4 q0 = ef[(long)ej * 8 + g];
                uint4 q1 = ef[(long)ej * 8 + 4 + g];
                bf0 = *reinterpret_cast<bf16x8*>(&q0);
                bf1 = *reinterpret_cast<bf16x8*>(&q1);
            } else {
                const float4* ef = (const float4*)edge_feat;
                long base = (long)ej * 16 + g * 2;
                float4 x0 = ef[base], x1 = ef[base + 1];
                float4 y0 = ef[base + 8], y1 = ef[base + 9];
                bf0[0] = (short)f2b_bits(x0.x); bf0[1] = (short)f2b_bits(x0.y);
                bf0[2] = (short)f2b_bits(x0.z); bf0[3] = (short)f2b_bits(x0.w);
                bf0[4] = (short)f2b_bits(x1.x); bf0[5] = (short)f2b_bits(x1.y);
                bf0[6] = (short)f2b_bits(x1.z); bf0[7] = (short)f2b_bits(x1.w);
                bf1[0] = (short)f2b_bits(y0.x); bf1[1] = (short)f2b_bits(y0.y);
                bf1[2] = (short)f2b_bits(y0.z); bf1[3] = (short)f2b_bits(y0.w);
                bf1[4] = (short)f2b_bits(y1.x); bf1[5] = (short)f2b_bits(y1.y);
                bf1[6] = (short)f2b_bits(y1.z); bf1[7] = (short)f2b_bits(y1.w);
            }
            const bool valid = je < deg;
#pragma unroll
            for (int mt = 0; mt < 8; mt++) {
                float4 b4 = *(const float4*)(w + OFF_BEDGE + mt * 16 + g * 4);
                f32x4 c = {b4.x, b4.y, b4.z, b4.w};   // bias rides in C-init
                c = __builtin_amdgcn_mfma_f32_16x16x32_bf16(wfb[(mt * 2 + 0) * 64 + lane], bf0, c, 0, 0, 0);
                c = __builtin_amdgcn_mfma_f32_16x16x32_bf16(wfb[(mt * 2 + 1) * 64 + lane], bf1, c, 0, 0, 0);
                float v0 = c[0], v1 = c[1], v2 = c[2], v3 = c[3];
                v0 = v0 > 0.f ? v0 : __expf(v0) - 1.f;
                v1 = v1 > 0.f ? v1 : __expf(v1) - 1.f;
                v2 = v2 > 0.f ? v2 : __expf(v2) - 1.f;
                v3 = v3 > 0.f ? v3 : __expf(v3) - 1.f;
                if (!valid) { v0 = v1 = v2 = v3 = -3.0e38f; }
#pragma unroll
                for (int mm = 1; mm < 16; mm <<= 1) {
                    v0 = fmaxf(v0, __shfl_xor(v0, mm));
                    v1 = fmaxf(v1, __shfl_xor(v1, mm));
                    v2 = fmaxf(v2, __shfl_xor(v2, mm));
                    v3 = fmaxf(v3, __shfl_xor(v3, mm));
                }
                if ((lane & 15) == 0) {
                    float4* vp = (float4*)&vm[mt * 16 + g * 4];
                    if (nt == 0) {
                        *vp = make_float4(v0, v1, v2, v3);
                    } else {
                        float4 o = *vp;
                        *vp = make_float4(fmaxf(o.x, v0), fmaxf(o.y, v1),
                                          fmaxf(o.z, v2), fmaxf(o.w, v3));
                    }
                }
            }
        }
        if (deg > 64) {   // ultra-cold overflow: scalar per-column path
            for (int jj = 64; jj < deg; jj++) {
                long e = perm[r0 + jj];
#pragma unroll 1
                for (int p = 0; p < 2; p++) {
                    int col = lane + p * 64;
                    const float4* wt4 = (const float4*)(w + OFF_WEDGE_T + col * EDGE_DIM);
                    float acc = w[OFF_BEDGE + col];
                    for (int kk = 0; kk < 16; kk++) {
                        float4 wv4 = wt4[kk];
                        float xx, xy, xz, xw;
                        if (isbf) {
                            u64 q = ((const u64*)edge_feat)[e * 16 + kk];
                            xx = b2f_raw((u16)q); xy = b2f_raw((u16)(q >> 16));
                            xz = b2f_raw((u16)(q >> 32)); xw = b2f_raw((u16)(q >> 48));
                        } else {
                            float4 xf = ((const float4*)edge_feat)[e * 16 + kk];
                            xx = xf.x; xy = xf.y; xz = xf.z; xw = xf.w;
                        }
                        acc += xx * wv4.x + xy * wv4.y + xz * wv4.z + xw * wv4.w;
                    }
                    float el = acc > 0.f ? acc : __expf(acc) - 1.f;
                    vm[col] = fmaxf(vm[col], el);
                }
            }
        }
        float2 vv = *(float2*)&vm[lane * 2];
        ((u32*)edge_max)[(long)n * 64 + lane] =
            (u32)f2b_bits(vv.x) | ((u32)f2b_bits(vv.y) << 16);
    }
}

// ---------- fused gate + output projection on MFMA ----------
#define FUSE_PAD 134
__global__ __launch_bounds__(256, 4) void k_fuse(const bf16* __restrict__ h_node,
                                              const bf16* __restrict__ edge_max,
                                              const float* __restrict__ w, const int* __restrict__ flag,
                                              bf16* __restrict__ out_b, float* __restrict__ out_f) {
    __shared__ float s_g[4][16][FUSE_PAD];
    const int wv = threadIdx.x >> 6;
    const int lane = threadIdx.x & 63;
    const int g = lane >> 4, j16 = lane & 15;
    const int isbf = flag[0];
    const long row0 = (long)blockIdx.x * 64 + wv * 16;
    if (row0 >= N_NODES) return;
    float (*g32)[FUSE_PAD] = s_g[wv];

    long jr = row0 + j16; if (jr >= N_NODES) jr = N_NODES - 1;
    uint4 hnf[4], emf[4];
    const uint4* hp = (const uint4*)h_node;
    const uint4* ep = (const uint4*)edge_max;
#pragma unroll
    for (int tt = 0; tt < 4; tt++) {
        hnf[tt] = hp[jr * 16 + tt * 4 + g];
        emf[tt] = ep[jr * 16 + tt * 4 + g];
    }
    const bf16x8* wg = (const bf16x8*)(w + OFF_WFG);
    const bf16x8* wo_hi = (const bf16x8*)(w + OFF_WFO_HI);
    const bf16x8* wo_lo = (const bf16x8*)(w + OFF_WFO_LO);

    // ---- gate GEMM: k=256 (hn: tt0-3, em: tt4-7) -> logits to LDS ----
#pragma unroll
    for (int ct = 0; ct < 8; ct++) {
        float bg = w[OFF_BGATE + ct * 16 + j16];
        f32x4 c = {bg, bg, bg, bg};
#pragma unroll
        for (int tt = 0; tt < 4; tt++)
            c = __builtin_amdgcn_mfma_f32_16x16x32_bf16(*reinterpret_cast<bf16x8*>(&hnf[tt]),
                                                        wg[(ct * 8 + tt) * 64 + lane], c, 0, 0, 0);
#pragma unroll
        for (int tt = 0; tt < 4; tt++)
            c = __builtin_amdgcn_mfma_f32_16x16x32_bf16(*reinterpret_cast<bf16x8*>(&emf[tt]),
                                                        wg[(ct * 8 + 4 + tt) * 64 + lane], c, 0, 0, 0);
#pragma unroll
        for (int r = 0; r < 4; r++) g32[g * 4 + r][ct * 16 + j16] = c[r];
    }

    // ---- fused bf16 A-frags: sigmoid(gate) combined with register hn/em ----
    uint4 ff[4];
#pragma unroll
    for (int tt = 0; tt < 4; tt++) {
        u32 wds[4];
        const float* gr = &g32[j16][tt * 32 + 8 * g];
#pragma unroll
        for (int s2 = 0; s2 < 4; s2++) {
            float glo = gr[s2 * 2], ghi = gr[s2 * 2 + 1];
            u32 hw = ((const u32*)&hnf[tt])[s2];
            u32 ew = ((const u32*)&emf[tt])[s2];
            float slo = 1.f / (1.f + __expf(-glo));
            float shi = 1.f / (1.f + __expf(-ghi));
            float flo = slo * lo16(hw) + (1.f - slo) * lo16(ew);
            float fhi = shi * hi16(hw) + (1.f - shi) * hi16(ew);
            wds[s2] = (u32)f2b_bits(flo) | ((u32)f2b_bits(fhi) << 16);
        }
        ff[tt] = make_uint4(wds[0], wds[1], wds[2], wds[3]);
    }

    // ---- out GEMM: k=128, hi+lo split weights -> D to LDS ----
#pragma unroll
    for (int ct = 0; ct < 8; ct++) {
        float bo = w[OFF_BOUT + ct * 16 + j16];
        f32x4 c = {bo, bo, bo, bo};
#pragma unroll
        for (int tt = 0; tt < 4; tt++) {
            c = __builtin_amdgcn_mfma_f32_16x16x32_bf16(*reinterpret_cast<bf16x8*>(&ff[tt]),
                                                        wo_hi[(ct * 4 + tt) * 64 + lane], c, 0, 0, 0);
            c = __builtin_amdgcn_mfma_f32_16x16x32_bf16(*reinterpret_cast<bf16x8*>(&ff[tt]),
                                                        wo_lo[(ct * 4 + tt) * 64 + lane], c, 0, 0, 0);
        }
#pragma unroll
        for (int r = 0; r < 4; r++) g32[g * 4 + r][ct * 16 + j16] = c[r];
    }

    // ---- coalesced store (row it, lane = col pair) ----
    for (int it = 0; it < 16; it++) {
        long rr = row0 + it;
        if (rr >= N_NODES) break;
        float v0 = g32[it][lane * 2], v1 = g32[it][lane * 2 + 1];
        if (isbf) {
            ((u32*)out_b)[rr * 64 + lane] = (u32)f2b_bits(v0) | ((u32)f2b_bits(v1) << 16);
        } else {
            ((float2*)out_f)[rr * 64 + lane] = make_float2(v0, v1);
        }
    }
}

extern "C" void kernel_launch(void* const* d_in, const int* in_sizes, int n_in,
                              void* d_out, int out_size, void* d_ws, size_t ws_size,
                              hipStream_t stream) {
    const void* node_feat = d_in[0];
    const void* edge_feat = d_in[1];
    const int* src = (const int*)d_in[2];
    const int* dst = (const int*)d_in[3];

    // workspace layout (bytes), total ~52.5 MB (proven-safe < 59.6 MB):
    //   0        .. 12.8M : f_src   bf16 [N][128]
    //   12.8M    .. 25.6M : f_dst   bf16 [N][128]  -> edge_max overlays (same [n] slot,
    //                       read-before-write within the owning wave)
    //   32.0M    .. 44.8M : h_node  bf16 [N][128]
    //   44.8M    ..       : deg, rowptr, perm, wcanon(+frags 675KB), flag, rank
    char* ws = (char*)d_ws;
    bf16* f_src = (bf16*)ws;
    bf16* f_dst = (bf16*)(ws + 12800000);
    bf16* edge_max = (bf16*)(ws + 12800000);  // overlays f_dst; node n's wave reads
                                              // f_dst[n] before writing edge_max[n]
    bf16* h_node = (bf16*)(ws + 32000000);
    int* deg = (int*)(ws + 44800000);
    int* rowptr = (int*)(ws + 45000000);
    int* perm = (int*)(ws + 45400016);
    float* wcanon = (float*)(ws + 48600032);  // 168704 floats -> ends 49274848
    int* flag = (int*)(ws + 49274848);
    int* rank = (int*)(ws + 49280000);        // 3.2MB -> ends 52480000

    bf16* out_b = (bf16*)d_out;
    float* out_f = (float*)d_out;
    bf16* out_a_b = out_b + (size_t)N_NODES * OUT_DIM;
    float* out_a_f = out_f + (size_t)N_NODES * OUT_DIM;

    k_init<<<(N_NODES + 255) / 256, 256, 0, stream>>>(node_feat, flag, deg);
    k_prep<<<WCONV_BLOCKS + HIST_BLOCKS, 256, 0, stream>>>(
        d_in[4], d_in[5], d_in[6], d_in[7], d_in[8], d_in[9], d_in[10],
        d_in[11], d_in[12], d_in[13], d_in[14], wcanon, flag, dst, deg, rank);
    k_scan<<<1, 1024, 0, stream>>>(deg, rowptr);
    k_pp<<<PROJ_BLOCKS + HIST_BLOCKS, 256, 0, stream>>>(node_feat, wcanon, flag, f_src, f_dst,
                                                        dst, rowptr, rank, perm);
    k_node_agg<<<N_NODES / 4, 256, 0, stream>>>(rowptr, perm, src, f_src, f_dst, edge_feat,
                                                wcanon, flag, h_node, edge_max, out_a_b, out_a_f);
    k_fuse<<<(N_NODES + 63) / 64, 256, 0, stream>>>(h_node, edge_max, wcanon, flag, out_b, out_f);
}

// Round 12
// 780.465 us; speedup vs baseline: 1.1264x; 1.1264x over previous
//
#include <hip/hip_runtime.h>
#include <hip/hip_bf16.h>

// AdaptiveEdgeGAT: N=50000, E=800000, IN=OUT=128, EDGE=64, H=4, D=32
// CSR (sort-by-dst) + gather-based segmented reductions.
// R1: wave-per-node node_agg. R2: edge-GEMM on MFMA. R4: logits fused in.
// R5: rank-from-atomic hist + atomic-free permute. R6: k_fuse on MFMA.
// R7: k_proj on MFMA. R8: (256,4)/64-VGPR + LDS f_src row cache.
// R9/R10: fat-kernel overlaps + merged node_agg; reg-prefetch reverted (spill).
// R11: (256,5) squeezed VGPR 64->48 -> spill (WRITE 199->612MB). THIRD proof:
//      this kernel needs 64 VGPR; never raise the launch-bound min.
// R12: CAPR 32->24 ONLY (LDS 39.9->31.2KB): runtime occupancy 4->5 blocks/CU
//      with launch_bounds(256,4) untouched -> VGPR stays 64, no spill.

#define N_NODES 50000
#define N_EDGES 800000
#define IN_DIM 128
#define OUT_DIM 128
#define EDGE_DIM 64
#define HEADS 4
#define HEAD_DIM 32
#define NEG_SLOPE 0.2f

typedef __hip_bfloat16 bf16;
typedef unsigned short u16;
typedef unsigned int u32;
typedef unsigned long long u64;
typedef __attribute__((ext_vector_type(8))) short bf16x8;
typedef __attribute__((ext_vector_type(4))) float f32x4;

// canonical f32 weight-block offsets (floats)
#define OFF_WSRC 0
#define OFF_BSRC 16384
#define OFF_WDST 16512
#define OFF_BDST 32896
#define OFF_ATTN 33024
#define OFF_WEDGE 33152
#define OFF_BEDGE 41344
#define OFF_WGATE 41472
#define OFF_BGATE 74240
#define OFF_WOUT 74368
#define OFF_BOUT 90752
#define OFF_WEDGE_T 90880   // transposed W_edge: [col][k] = [128][64] (f32, cold path)
#define OFF_WFRAG 99072     // bf16 B-fragments of W_edge^T: 4096 u32 words (16KB)
#define OFF_WFG 103168      // bf16 B-fragments of W_gate: [ct8][tt8][64][4w] = 16384
#define OFF_WFO_HI 119552   // bf16 B-fragments of W_out (hi): [ct8][tt4][64][4w] = 8192
#define OFF_WFO_LO 127744   // bf16 B-fragments of W_out (lo residual): 8192
#define OFF_WFS_HI 135936   // W_src hi fragments: 8192
#define OFF_WFS_LO 144128   // W_src lo fragments: 8192
#define OFF_WFD_HI 152320   // W_dst hi fragments: 8192
#define OFF_WFD_LO 160512   // W_dst lo fragments: 8192
#define W_TOTAL 168704

#define WCONV_BLOCKS 659    // W_TOTAL/256
#define HIST_BLOCKS 3125    // ceil(E/256)
#define PROJ_BLOCKS 782     // ceil(N/64)

__device__ __forceinline__ float b2f_raw(u16 v) {
    return __uint_as_float(((u32)v) << 16);
}
__device__ __forceinline__ float b2f(bf16 v) { return __bfloat162float(v); }
__device__ __forceinline__ float loadin(const void* p, long i, int isbf) {
    return isbf ? b2f_raw(((const u16*)p)[i]) : ((const float*)p)[i];
}
__device__ __forceinline__ float lo16(u32 v) { return __uint_as_float(v << 16); }
__device__ __forceinline__ float hi16(u32 v) { return __uint_as_float(v & 0xFFFF0000u); }
__device__ __forceinline__ u16 f2b_bits(float x) {
    bf16 t = __float2bfloat16(x);
    return *reinterpret_cast<u16*>(&t);
}
// per-col-pair logit partial: leaky_relu(fs + fd) dot attn_w (2 cols of this lane)
__device__ __forceinline__ float logit_part(u32 v, float fdlo, float fdhi, float2 awc) {
    float x0 = lo16(v) + fdlo; x0 = x0 > 0.f ? x0 : NEG_SLOPE * x0;
    float x1 = hi16(v) + fdhi; x1 = x1 > 0.f ? x1 : NEG_SLOPE * x1;
    return x0 * awc.x + x1 * awc.y;
}
// sum across the 16-lane head group
__device__ __forceinline__ float red16(float r) {
    r += __shfl_xor(r, 1); r += __shfl_xor(r, 2);
    r += __shfl_xor(r, 4); r += __shfl_xor(r, 8);
    return r;
}

// ---------- init: dtype detect (block 0) + zero degree counters (all blocks) ----------
__global__ __launch_bounds__(256) void k_init(const void* node, int* flag, int* __restrict__ deg) {
    int i = blockIdx.x * 256 + threadIdx.x;
    if (i < N_NODES) deg[i] = 0;
    if (blockIdx.x == 0) {
        __shared__ int cnt[256];
        int c = 0;
        for (int j = threadIdx.x; j < 8192; j += 256) {
            float v = b2f_raw(((const u16*)node)[j]);
            float a = fabsf(v);
            if ((a >= 1e-4f && a <= 50.f) || v == 0.f) c++;
        }
        cnt[threadIdx.x] = c;
        __syncthreads();
        for (int s = 128; s > 0; s >>= 1) {
            if (threadIdx.x < s) cnt[threadIdx.x] += cnt[threadIdx.x + s];
            __syncthreads();
        }
        if (threadIdx.x == 0) flag[0] = (cnt[0] >= (8192 * 85) / 100) ? 1 : 0;
    }
}

// ---------- fused: weight canonicalization (blocks 0..658) || degree histogram ----------
__global__ __launch_bounds__(256) void k_prep(const void* Wsrc, const void* bsrc,
                                              const void* Wdst, const void* bdst,
                                              const void* attn, const void* Wedge, const void* bedge,
                                              const void* Wgate, const void* bgate,
                                              const void* Wout, const void* bout,
                                              float* w, const int* flag,
                                              const int* __restrict__ dst, int* __restrict__ deg,
                                              int* __restrict__ rank) {
    if (blockIdx.x >= WCONV_BLOCKS) {
        int e = (blockIdx.x - WCONV_BLOCKS) * 256 + threadIdx.x;
        if (e < N_EDGES) rank[e] = atomicAdd(&deg[dst[e]], 1);
        return;
    }
    int i = blockIdx.x * 256 + threadIdx.x;
    if (i >= W_TOTAL) return;
    int f = flag[0];
    const void* p; long off;
    if (i < OFF_BSRC)         { p = Wsrc;  off = i - OFF_WSRC; }
    else if (i < OFF_WDST)    { p = bsrc;  off = i - OFF_BSRC; }
    else if (i < OFF_BDST)    { p = Wdst;  off = i - OFF_WDST; }
    else if (i < OFF_ATTN)    { p = bdst;  off = i - OFF_BDST; }
    else if (i < OFF_WEDGE)   { p = attn;  off = i - OFF_ATTN; }
    else if (i < OFF_BEDGE)   { p = Wedge; off = i - OFF_WEDGE; }
    else if (i < OFF_WGATE)   { p = bedge; off = i - OFF_BEDGE; }
    else if (i < OFF_BGATE)   { p = Wgate; off = i - OFF_WGATE; }
    else if (i < OFF_WOUT)    { p = bgate; off = i - OFF_BGATE; }
    else if (i < OFF_BOUT)    { p = Wout;  off = i - OFF_WOUT; }
    else if (i < OFF_WEDGE_T) { p = bout;  off = i - OFF_BOUT; }
    else if (i < OFF_WFRAG) { // transposed W_edge: wt[col*64+k] = W_edge[k*128+col]
        int idx = i - OFF_WEDGE_T;
        int col = idx >> 6, k = idx & 63;
        w[i] = loadin(Wedge, (long)k * OUT_DIM + col, f);
        return;
    } else if (i < OFF_WFG) {
        // W_edge fragments: wdx = mt*512 + tt*256 + l*4 + s/2 (k in 0..63)
        int wdx = i - OFF_WFRAG;
        int sp = (wdx & 3) * 2;
        int l = (wdx >> 2) & 63;
        int tt = (wdx >> 8) & 1;
        int mt = wdx >> 9;
        int k0 = tt * 32 + ((l >> 4) << 3);
        int col = mt * 16 + (l & 15);
        float v0 = loadin(Wedge, (long)(k0 + sp) * OUT_DIM + col, f);
        float v1 = loadin(Wedge, (long)(k0 + sp + 1) * OUT_DIM + col, f);
        *(u32*)&w[i] = (u32)f2b_bits(v0) | ((u32)f2b_bits(v1) << 16);
        return;
    } else if (i < OFF_WFO_HI) {
        // W_gate fragments: wdx = ct*2048 + tt*256 + l*4 + s/2 (k in 0..255)
        int wdx = i - OFF_WFG;
        int sp = (wdx & 3) * 2;
        int l = (wdx >> 2) & 63;
        int tt = (wdx >> 8) & 7;
        int ct = wdx >> 11;
        int k0 = tt * 32 + ((l >> 4) << 3);
        int c = ct * 16 + (l & 15);
        float v0 = loadin(Wgate, (long)(k0 + sp) * OUT_DIM + c, f);
        float v1 = loadin(Wgate, (long)(k0 + sp + 1) * OUT_DIM + c, f);
        *(u32*)&w[i] = (u32)f2b_bits(v0) | ((u32)f2b_bits(v1) << 16);
        return;
    } else {
        // 128-k matrices (W_out/W_src/W_dst, hi or lo): wdx = ct*1024 + tt*256 + l*4 + s/2
        const void* M; int base; int wantlo;
        if (i < OFF_WFO_LO)      { M = Wout; base = OFF_WFO_HI; wantlo = 0; }
        else if (i < OFF_WFS_HI) { M = Wout; base = OFF_WFO_LO; wantlo = 1; }
        else if (i < OFF_WFS_LO) { M = Wsrc; base = OFF_WFS_HI; wantlo = 0; }
        else if (i < OFF_WFD_HI) { M = Wsrc; base = OFF_WFS_LO; wantlo = 1; }
        else if (i < OFF_WFD_LO) { M = Wdst; base = OFF_WFD_HI; wantlo = 0; }
        else                     { M = Wdst; base = OFF_WFD_LO; wantlo = 1; }
        int wdx = i - base;
        int sp = (wdx & 3) * 2;
        int l = (wdx >> 2) & 63;
        int tt = (wdx >> 8) & 3;
        int ct = wdx >> 10;
        int k0 = tt * 32 + ((l >> 4) << 3);
        int c = ct * 16 + (l & 15);
        float v0 = loadin(M, (long)(k0 + sp) * OUT_DIM + c, f);
        float v1 = loadin(M, (long)(k0 + sp + 1) * OUT_DIM + c, f);
        if (wantlo) {
            v0 = v0 - b2f_raw(f2b_bits(v0));
            v1 = v1 - b2f_raw(f2b_bits(v1));
        }
        *(u32*)&w[i] = (u32)f2b_bits(v0) | ((u32)f2b_bits(v1) << 16);
        return;
    }
    w[i] = loadin(p, off, f);
}

// ---------- exclusive prefix sum: thread-coarsened, 22 barriers total ----------
#define SCAN_CHUNK 49   // 49*1024 = 50176 >= N_NODES
__global__ __launch_bounds__(1024) void k_scan(const int* __restrict__ deg,
                                               int* __restrict__ rowptr) {
    __shared__ int part[1024];
    int tid = threadIdx.x;
    int base = tid * SCAN_CHUNK;
    int s = 0;
    for (int j = 0; j < SCAN_CHUNK; j++) {
        int i = base + j;
        if (i < N_NODES) s += deg[i];
    }
    part[tid] = s;
    __syncthreads();
    for (int st = 1; st < 1024; st <<= 1) {
        int v = (tid >= st) ? part[tid - st] : 0;
        __syncthreads();
        part[tid] += v;
        __syncthreads();
    }
    int run = (tid == 0) ? 0 : part[tid - 1];
    for (int j = 0; j < SCAN_CHUNK; j++) {
        int i = base + j;
        if (i < N_NODES) {
            rowptr[i] = run;
            run += deg[i];
        }
    }
    if (N_NODES >= base && N_NODES < base + SCAN_CHUNK) rowptr[N_NODES] = run;
}

// ---------- fused: node projections on MFMA (blocks 0..781) || edge permute ----------
#define PROJ_PAD 134
__global__ __launch_bounds__(256, 4) void k_pp(const void* __restrict__ node,
                                              const float* __restrict__ w, const int* __restrict__ flag,
                                              bf16* __restrict__ f_src, bf16* __restrict__ f_dst,
                                              const int* __restrict__ dst,
                                              const int* __restrict__ rowptr,
                                              const int* __restrict__ rank,
                                              int* __restrict__ perm) {
    if (blockIdx.x >= PROJ_BLOCKS) {
        int e = (blockIdx.x - PROJ_BLOCKS) * 256 + threadIdx.x;
        if (e < N_EDGES) perm[rowptr[dst[e]] + rank[e]] = e;
        return;
    }
    __shared__ float s_t[4][16][PROJ_PAD];
    const int wv = threadIdx.x >> 6;
    const int lane = threadIdx.x & 63;
    const int g = lane >> 4, j16 = lane & 15;
    const int isbf = flag[0];
    const long row0 = (long)blockIdx.x * 64 + wv * 16;
    if (row0 >= N_NODES) return;
    float (*t32)[PROJ_PAD] = s_t[wv];
    long jr = row0 + j16; if (jr >= N_NODES) jr = N_NODES - 1;

    uint4 ah[4], al[4];
    if (isbf) {
        const uint4* np = (const uint4*)node;
#pragma unroll
        for (int tt = 0; tt < 4; tt++) ah[tt] = np[jr * 16 + tt * 4 + g];
    } else {
        const float4* np = (const float4*)node;
#pragma unroll
        for (int tt = 0; tt < 4; tt++) {
            float4 x0 = np[jr * 32 + tt * 8 + g * 2];
            float4 x1 = np[jr * 32 + tt * 8 + g * 2 + 1];
            float xv[8] = {x0.x, x0.y, x0.z, x0.w, x1.x, x1.y, x1.z, x1.w};
            u32 hw[4], lw[4];
#pragma unroll
            for (int s2 = 0; s2 < 4; s2++) {
                u16 h0 = f2b_bits(xv[s2 * 2]), h1 = f2b_bits(xv[s2 * 2 + 1]);
                float r0 = xv[s2 * 2] - b2f_raw(h0);
                float r1 = xv[s2 * 2 + 1] - b2f_raw(h1);
                hw[s2] = (u32)h0 | ((u32)h1 << 16);
                lw[s2] = (u32)f2b_bits(r0) | ((u32)f2b_bits(r1) << 16);
            }
            ah[tt] = make_uint4(hw[0], hw[1], hw[2], hw[3]);
            al[tt] = make_uint4(lw[0], lw[1], lw[2], lw[3]);
        }
    }

    const bf16x8* wsh = (const bf16x8*)(w + OFF_WFS_HI);
    const bf16x8* wsl = (const bf16x8*)(w + OFF_WFS_LO);
    const bf16x8* wdh = (const bf16x8*)(w + OFF_WFD_HI);
    const bf16x8* wdl = (const bf16x8*)(w + OFF_WFD_LO);

    // ---- f_src = x @ W_src + b ----
#pragma unroll
    for (int ct = 0; ct < 8; ct++) {
        float bs = w[OFF_BSRC + ct * 16 + j16];
        f32x4 c = {bs, bs, bs, bs};
#pragma unroll
        for (int tt = 0; tt < 4; tt++) {
            bf16x8 a = *reinterpret_cast<bf16x8*>(&ah[tt]);
            c = __builtin_amdgcn_mfma_f32_16x16x32_bf16(a, wsh[(ct * 4 + tt) * 64 + lane], c, 0, 0, 0);
            c = __builtin_amdgcn_mfma_f32_16x16x32_bf16(a, wsl[(ct * 4 + tt) * 64 + lane], c, 0, 0, 0);
        }
        if (!isbf) {
#pragma unroll
            for (int tt = 0; tt < 4; tt++)
                c = __builtin_amdgcn_mfma_f32_16x16x32_bf16(*reinterpret_cast<bf16x8*>(&al[tt]),
                                                            wsh[(ct * 4 + tt) * 64 + lane], c, 0, 0, 0);
        }
#pragma unroll
        for (int r = 0; r < 4; r++) t32[g * 4 + r][ct * 16 + j16] = c[r];
    }
    for (int it = 0; it < 16; it++) {
        long rr = row0 + it;
        if (rr >= N_NODES) break;
        ((u32*)f_src)[rr * 64 + lane] =
            (u32)f2b_bits(t32[it][lane * 2]) | ((u32)f2b_bits(t32[it][lane * 2 + 1]) << 16);
    }

    // ---- f_dst = x @ W_dst + b ----
#pragma unroll
    for (int ct = 0; ct < 8; ct++) {
        float bd = w[OFF_BDST + ct * 16 + j16];
        f32x4 c = {bd, bd, bd, bd};
#pragma unroll
        for (int tt = 0; tt < 4; tt++) {
            bf16x8 a = *reinterpret_cast<bf16x8*>(&ah[tt]);
            c = __builtin_amdgcn_mfma_f32_16x16x32_bf16(a, wdh[(ct * 4 + tt) * 64 + lane], c, 0, 0, 0);
            c = __builtin_amdgcn_mfma_f32_16x16x32_bf16(a, wdl[(ct * 4 + tt) * 64 + lane], c, 0, 0, 0);
        }
        if (!isbf) {
#pragma unroll
            for (int tt = 0; tt < 4; tt++)
                c = __builtin_amdgcn_mfma_f32_16x16x32_bf16(*reinterpret_cast<bf16x8*>(&al[tt]),
                                                            wdh[(ct * 4 + tt) * 64 + lane], c, 0, 0, 0);
        }
#pragma unroll
        for (int r = 0; r < 4; r++) t32[g * 4 + r][ct * 16 + j16] = c[r];
    }
    for (int it = 0; it < 16; it++) {
        long rr = row0 + it;
        if (rr >= N_NODES) break;
        ((u32*)f_dst)[rr * 64 + lane] =
            (u32)f2b_bits(t32[it][lane * 2]) | ((u32)f2b_bits(t32[it][lane * 2 + 1]) << 16);
    }
}

// ---------- per-node aggregation: wave-per-node, fused logits+softmax+agg ----------
// All LDS wave-private -> zero barriers. Single dispatch.
// R12: CAPR 24 (31.2KB LDS -> 5 blocks/CU at runtime); launch_bounds(256,4)
// UNTOUCHED so allocator keeps 64 VGPR (R7/R9/R11: squeezing below 64 = spill).
#define CAPR 24   // cached f_src rows per node (P(deg>24)~2% re-gathers L2-warm)
__global__ __launch_bounds__(256, 4) void k_node_agg(const int* __restrict__ rowptr,
                                                  const int* __restrict__ perm,
                                                  const int* __restrict__ src,
                                                  const bf16* __restrict__ f_src,
                                                  const bf16* __restrict__ f_dst,
                                                  const void* __restrict__ edge_feat,
                                                  const float* __restrict__ w, const int* __restrict__ flag,
                                                  bf16* __restrict__ h_node, bf16* __restrict__ edge_max,
                                                  bf16* __restrict__ out_a_b, float* __restrict__ out_a_f) {
    __shared__ int s_esrc[4][64];
    __shared__ __align__(16) float s_a[4][64][4];
    __shared__ __align__(16) float s_vmax[4][128];
    __shared__ u32 s_xs[4][CAPR][64];   // cached f_src rows (u32 = 2 bf16 cols/lane)

    const int wv = threadIdx.x >> 6;
    const int lane = threadIdx.x & 63;
    const int n = blockIdx.x * 4 + wv;
    const int isbf = flag[0];
    const int r0 = rowptr[n], r1 = rowptr[n + 1];
    const int deg = r1 - r0;

    int* esrc = s_esrc[wv];
    float (*aA)[4] = s_a[wv];
    float* vm = s_vmax[wv];
    u32 (*xs)[64] = s_xs[wv];

    const u32* fs32 = (const u32*)f_src;
    const int g = lane >> 4;          // head group of this lane's column pair
    const int dm = deg < 64 ? deg : 64;

    // ---- Phase 1: per-lane edge metadata ----
    int e0 = 0, sv = 0;
    if (lane < deg) {
        e0 = perm[r0 + lane];
        sv = src[e0];
        esrc[lane] = sv;
    }

    // ---- Phase L: fused GATv2 logits (+ row cache fill) ----
    u32 fdw = ((const u32*)f_dst)[(long)n * 64 + lane];
    const float fdlo = lo16(fdw), fdhi = hi16(fdw);
    const float2 awc = *(const float2*)&w[OFF_ATTN + lane * 2];
    {
        int j = 0;
        for (; j + 4 <= dm; j += 4) {
            int sA = __shfl(sv, j), sB = __shfl(sv, j + 1);
            int sC = __shfl(sv, j + 2), sD = __shfl(sv, j + 3);
            u32 vA = fs32[(long)sA * 64 + lane];
            u32 vB = fs32[(long)sB * 64 + lane];
            u32 vC = fs32[(long)sC * 64 + lane];
            u32 vD = fs32[(long)sD * 64 + lane];
            if (j + 3 < CAPR) {
                xs[j][lane] = vA; xs[j + 1][lane] = vB;
                xs[j + 2][lane] = vC; xs[j + 3][lane] = vD;
            }
            float rA = red16(logit_part(vA, fdlo, fdhi, awc));
            float rB = red16(logit_part(vB, fdlo, fdhi, awc));
            float rC = red16(logit_part(vC, fdlo, fdhi, awc));
            float rD = red16(logit_part(vD, fdlo, fdhi, awc));
            if ((lane & 15) == 0) {
                aA[j][g] = rA; aA[j + 1][g] = rB;
                aA[j + 2][g] = rC; aA[j + 3][g] = rD;
            }
        }
        for (; j < dm; j++) {
            int sA = __shfl(sv, j);
            u32 vA = fs32[(long)sA * 64 + lane];
            if (j < CAPR) xs[j][lane] = vA;
            float rA = red16(logit_part(vA, fdlo, fdhi, awc));
            if ((lane & 15) == 0) aA[j][g] = rA;
        }
    }

    // ---- Phase 2: softmax in registers (lane j owns edge j) ----
    float l0 = -3.0e38f, l1 = -3.0e38f, l2 = -3.0e38f, l3 = -3.0e38f;
    if (lane < deg) {
        float4 lv = *(float4*)aA[lane];
        l0 = lv.x; l1 = lv.y; l2 = lv.z; l3 = lv.w;
    }
    float m0 = l0, m1 = l1, m2 = l2, m3 = l3;
#pragma unroll
    for (int s = 1; s < 64; s <<= 1) {
        m0 = fmaxf(m0, __shfl_xor(m0, s));
        m1 = fmaxf(m1, __shfl_xor(m1, s));
        m2 = fmaxf(m2, __shfl_xor(m2, s));
        m3 = fmaxf(m3, __shfl_xor(m3, s));
    }
    for (int jj = 64; jj < deg; jj++) {   // cold: deg > 64 — cooperative logit, max
        int e = perm[r0 + jj];
        int s0 = src[e];
        u32 v = fs32[(long)s0 * 64 + lane];
        float red = red16(logit_part(v, fdlo, fdhi, awc));
        float q0 = __shfl(red, 0), q1 = __shfl(red, 16);
        float q2 = __shfl(red, 32), q3 = __shfl(red, 48);
        m0 = fmaxf(m0, q0); m1 = fmaxf(m1, q1);
        m2 = fmaxf(m2, q2); m3 = fmaxf(m3, q3);
    }
    float p0 = 0.f, p1 = 0.f, p2 = 0.f, p3 = 0.f;
    if (lane < deg) {
        p0 = __expf(l0 - m0); p1 = __expf(l1 - m1);
        p2 = __expf(l2 - m2); p3 = __expf(l3 - m3);
    }
    float t0 = p0, t1 = p1, t2 = p2, t3 = p3;
#pragma unroll
    for (int s = 1; s < 64; s <<= 1) {
        t0 += __shfl_xor(t0, s);
        t1 += __shfl_xor(t1, s);
        t2 += __shfl_xor(t2, s);
        t3 += __shfl_xor(t3, s);
    }
    for (int jj = 64; jj < deg; jj++) {   // cold: sum of overflow exps (uniform)
        int e = perm[r0 + jj];
        int s0 = src[e];
        u32 v = fs32[(long)s0 * 64 + lane];
        float red = red16(logit_part(v, fdlo, fdhi, awc));
        t0 += __expf(__shfl(red, 0) - m0);
        t1 += __expf(__shfl(red, 16) - m1);
        t2 += __expf(__shfl(red, 32) - m2);
        t3 += __expf(__shfl(red, 48) - m3);
    }
    const float i0 = 1.f / fmaxf(t0, 1e-9f);
    const float i1 = 1.f / fmaxf(t1, 1e-9f);
    const float i2 = 1.f / fmaxf(t2, 1e-9f);
    const float i3 = 1.f / fmaxf(t3, 1e-9f);
    if (lane < deg) {
        float a0 = p0 * i0, a1 = p1 * i1, a2 = p2 * i2, a3 = p3 * i3;
        *(float4*)aA[lane] = make_float4(a0, a1, a2, a3);
        if (isbf) {
            u64 pk = (u64)f2b_bits(a0) | ((u64)f2b_bits(a1) << 16)
                   | ((u64)f2b_bits(a2) << 32) | ((u64)f2b_bits(a3) << 48);
            ((u64*)out_a_b)[e0] = pk;
        } else {
            ((float4*)out_a_f)[e0] = make_float4(a0, a1, a2, a3);
        }
    }

    // ---- Phase 3a: message accumulate — cached rows from LDS, rest from global ----
    const int hsel = g;
    float acc0 = 0.f, acc1 = 0.f;
    const int capn = dm < CAPR ? dm : CAPR;
    int j = 0;
    for (; j + 4 <= capn; j += 4) {
        float a0 = aA[j][hsel], a1 = aA[j + 1][hsel];
        float a2 = aA[j + 2][hsel], a3 = aA[j + 3][hsel];
        u32 v0 = xs[j][lane];
        u32 v1 = xs[j + 1][lane];
        u32 v2 = xs[j + 2][lane];
        u32 v3 = xs[j + 3][lane];
        acc0 += lo16(v0) * a0 + lo16(v1) * a1 + lo16(v2) * a2 + lo16(v3) * a3;
        acc1 += hi16(v0) * a0 + hi16(v1) * a1 + hi16(v2) * a2 + hi16(v3) * a3;
    }
    for (; j < capn; j++) {
        float a0 = aA[j][hsel];
        u32 v0 = xs[j][lane];
        acc0 += lo16(v0) * a0;
        acc1 += hi16(v0) * a0;
    }
    for (; j < dm; j++) {   // deg in (CAPR,64]: re-gather (L2-warm)
        int s0 = esrc[j];
        float a0 = aA[j][hsel];
        u32 v0 = fs32[(long)s0 * 64 + lane];
        acc0 += lo16(v0) * a0;
        acc1 += hi16(v0) * a0;
    }
    if (deg > 64) {   // cold: cooperative logit -> a -> out_a + message
        float mh = (hsel & 2) ? ((hsel & 1) ? m3 : m2) : ((hsel & 1) ? m1 : m0);
        float ih = (hsel & 2) ? ((hsel & 1) ? i3 : i2) : ((hsel & 1) ? i1 : i0);
        for (int jj = 64; jj < deg; jj++) {
            int e = perm[r0 + jj];
            int s0 = src[e];
            u32 v = fs32[(long)s0 * 64 + lane];
            float red = red16(logit_part(v, fdlo, fdhi, awc));
            float q0 = __shfl(red, 0), q1 = __shfl(red, 16);
            float q2 = __shfl(red, 32), q3 = __shfl(red, 48);
            float a0 = __expf(q0 - m0) * i0, a1 = __expf(q1 - m1) * i1;
            float a2 = __expf(q2 - m2) * i2, a3 = __expf(q3 - m3) * i3;
            if (lane == 0) {
                if (isbf) {
                    u64 pk = (u64)f2b_bits(a0) | ((u64)f2b_bits(a1) << 16)
                           | ((u64)f2b_bits(a2) << 32) | ((u64)f2b_bits(a3) << 48);
                    ((u64*)out_a_b)[e] = pk;
                } else {
                    ((float4*)out_a_f)[e] = make_float4(a0, a1, a2, a3);
                }
            }
            float qh = (hsel & 2) ? ((hsel & 1) ? q3 : q2) : ((hsel & 1) ? q1 : q0);
            float ah = __expf(qh - mh) * ih;
            acc0 += lo16(v) * ah;
            acc1 += hi16(v) * ah;
        }
    }
    ((u32*)h_node)[n * 64 + lane] =
        (u32)f2b_bits(acc0) | ((u32)f2b_bits(acc1) << 16);

    // ---- Phase 3b: edge encoder GEMM on MFMA + column max ----
    if (deg == 0) {
        ((u32*)edge_max)[(long)n * 64 + lane] = 0u;
        return;
    }
    {
        const bf16x8* wfb = (const bf16x8*)(w + OFF_WFRAG);
        const int ntiles = deg >= 64 ? 4 : ((deg + 15) >> 4);
        for (int nt = 0; nt < ntiles; nt++) {
            const int je = nt * 16 + (lane & 15);
            const int ej = __shfl(e0, je);      // e0 defaults 0 for pad lanes (masked below)
            bf16x8 bf0, bf1;
            if (isbf) {
                const uint4* ef = (const uint4*)edge_feat;
                uint4 q0 = ef[(long)ej * 8 + g];
                uint4 q1 = ef[(long)ej * 8 + 4 + g];
                bf0 = *reinterpret_cast<bf16x8*>(&q0);
                bf1 = *reinterpret_cast<bf16x8*>(&q1);
            } else {
                const float4* ef = (const float4*)edge_feat;
                long base = (long)ej * 16 + g * 2;
                float4 x0 = ef[base], x1 = ef[base + 1];
                float4 y0 = ef[base + 8], y1 = ef[base + 9];
                bf0[0] = (short)f2b_bits(x0.x); bf0[1] = (short)f2b_bits(x0.y);
                bf0[2] = (short)f2b_bits(x0.z); bf0[3] = (short)f2b_bits(x0.w);
                bf0[4] = (short)f2b_bits(x1.x); bf0[5] = (short)f2b_bits(x1.y);
                bf0[6] = (short)f2b_bits(x1.z); bf0[7] = (short)f2b_bits(x1.w);
                bf1[0] = (short)f2b_bits(y0.x); bf1[1] = (short)f2b_bits(y0.y);
                bf1[2] = (short)f2b_bits(y0.z); bf1[3] = (short)f2b_bits(y0.w);
                bf1[4] = (short)f2b_bits(y1.x); bf1[5] = (short)f2b_bits(y1.y);
                bf1[6] = (short)f2b_bits(y1.z); bf1[7] = (short)f2b_bits(y1.w);
            }
            const bool valid = je < deg;
#pragma unroll
            for (int mt = 0; mt < 8; mt++) {
                float4 b4 = *(const float4*)(w + OFF_BEDGE + mt * 16 + g * 4);
                f32x4 c = {b4.x, b4.y, b4.z, b4.w};   // bias rides in C-init
                c = __builtin_amdgcn_mfma_f32_16x16x32_bf16(wfb[(mt * 2 + 0) * 64 + lane], bf0, c, 0, 0, 0);
                c = __builtin_amdgcn_mfma_f32_16x16x32_bf16(wfb[(mt * 2 + 1) * 64 + lane], bf1, c, 0, 0, 0);
                float v0 = c[0], v1 = c[1], v2 = c[2], v3 = c[3];
                v0 = v0 > 0.f ? v0 : __expf(v0) - 1.f;
                v1 = v1 > 0.f ? v1 : __expf(v1) - 1.f;
                v2 = v2 > 0.f ? v2 : __expf(v2) - 1.f;
                v3 = v3 > 0.f ? v3 : __expf(v3) - 1.f;
                if (!valid) { v0 = v1 = v2 = v3 = -3.0e38f; }
#pragma unroll
                for (int mm = 1; mm < 16; mm <<= 1) {
                    v0 = fmaxf(v0, __shfl_xor(v0, mm));
                    v1 = fmaxf(v1, __shfl_xor(v1, mm));
                    v2 = fmaxf(v2, __shfl_xor(v2, mm));
                    v3 = fmaxf(v3, __shfl_xor(v3, mm));
                }
                if ((lane & 15) == 0) {
                    float4* vp = (float4*)&vm[mt * 16 + g * 4];
                    if (nt == 0) {
                        *vp = make_float4(v0, v1, v2, v3);
                    } else {
                        float4 o = *vp;
                        *vp = make_float4(fmaxf(o.x, v0), fmaxf(o.y, v1),
                                          fmaxf(o.z, v2), fmaxf(o.w, v3));
                    }
                }
            }
        }
        if (deg > 64) {   // ultra-cold overflow: scalar per-column path
            for (int jj = 64; jj < deg; jj++) {
                long e = perm[r0 + jj];
#pragma unroll 1
                for (int p = 0; p < 2; p++) {
                    int col = lane + p * 64;
                    const float4* wt4 = (const float4*)(w + OFF_WEDGE_T + col * EDGE_DIM);
                    float acc = w[OFF_BEDGE + col];
                    for (int kk = 0; kk < 16; kk++) {
                        float4 wv4 = wt4[kk];
                        float xx, xy, xz, xw;
                        if (isbf) {
                            u64 q = ((const u64*)edge_feat)[e * 16 + kk];
                            xx = b2f_raw((u16)q); xy = b2f_raw((u16)(q >> 16));
                            xz = b2f_raw((u16)(q >> 32)); xw = b2f_raw((u16)(q >> 48));
                        } else {
                            float4 xf = ((const float4*)edge_feat)[e * 16 + kk];
                            xx = xf.x; xy = xf.y; xz = xf.z; xw = xf.w;
                        }
                        acc += xx * wv4.x + xy * wv4.y + xz * wv4.z + xw * wv4.w;
                    }
                    float el = acc > 0.f ? acc : __expf(acc) - 1.f;
                    vm[col] = fmaxf(vm[col], el);
                }
            }
        }
        float2 vv = *(float2*)&vm[lane * 2];
        ((u32*)edge_max)[(long)n * 64 + lane] =
            (u32)f2b_bits(vv.x) | ((u32)f2b_bits(vv.y) << 16);
    }
}

// ---------- fused gate + output projection on MFMA ----------
#define FUSE_PAD 134
__global__ __launch_bounds__(256, 4) void k_fuse(const bf16* __restrict__ h_node,
                                              const bf16* __restrict__ edge_max,
                                              const float* __restrict__ w, const int* __restrict__ flag,
                                              bf16* __restrict__ out_b, float* __restrict__ out_f) {
    __shared__ float s_g[4][16][FUSE_PAD];
    const int wv = threadIdx.x >> 6;
    const int lane = threadIdx.x & 63;
    const int g = lane >> 4, j16 = lane & 15;
    const int isbf = flag[0];
    const long row0 = (long)blockIdx.x * 64 + wv * 16;
    if (row0 >= N_NODES) return;
    float (*g32)[FUSE_PAD] = s_g[wv];

    long jr = row0 + j16; if (jr >= N_NODES) jr = N_NODES - 1;
    uint4 hnf[4], emf[4];
    const uint4* hp = (const uint4*)h_node;
    const uint4* ep = (const uint4*)edge_max;
#pragma unroll
    for (int tt = 0; tt < 4; tt++) {
        hnf[tt] = hp[jr * 16 + tt * 4 + g];
        emf[tt] = ep[jr * 16 + tt * 4 + g];
    }
    const bf16x8* wg = (const bf16x8*)(w + OFF_WFG);
    const bf16x8* wo_hi = (const bf16x8*)(w + OFF_WFO_HI);
    const bf16x8* wo_lo = (const bf16x8*)(w + OFF_WFO_LO);

    // ---- gate GEMM: k=256 (hn: tt0-3, em: tt4-7) -> logits to LDS ----
#pragma unroll
    for (int ct = 0; ct < 8; ct++) {
        float bg = w[OFF_BGATE + ct * 16 + j16];
        f32x4 c = {bg, bg, bg, bg};
#pragma unroll
        for (int tt = 0; tt < 4; tt++)
            c = __builtin_amdgcn_mfma_f32_16x16x32_bf16(*reinterpret_cast<bf16x8*>(&hnf[tt]),
                                                        wg[(ct * 8 + tt) * 64 + lane], c, 0, 0, 0);
#pragma unroll
        for (int tt = 0; tt < 4; tt++)
            c = __builtin_amdgcn_mfma_f32_16x16x32_bf16(*reinterpret_cast<bf16x8*>(&emf[tt]),
                                                        wg[(ct * 8 + 4 + tt) * 64 + lane], c, 0, 0, 0);
#pragma unroll
        for (int r = 0; r < 4; r++) g32[g * 4 + r][ct * 16 + j16] = c[r];
    }

    // ---- fused bf16 A-frags: sigmoid(gate) combined with register hn/em ----
    uint4 ff[4];
#pragma unroll
    for (int tt = 0; tt < 4; tt++) {
        u32 wds[4];
        const float* gr = &g32[j16][tt * 32 + 8 * g];
#pragma unroll
        for (int s2 = 0; s2 < 4; s2++) {
            float glo = gr[s2 * 2], ghi = gr[s2 * 2 + 1];
            u32 hw = ((const u32*)&hnf[tt])[s2];
            u32 ew = ((const u32*)&emf[tt])[s2];
            float slo = 1.f / (1.f + __expf(-glo));
            float shi = 1.f / (1.f + __expf(-ghi));
            float flo = slo * lo16(hw) + (1.f - slo) * lo16(ew);
            float fhi = shi * hi16(hw) + (1.f - shi) * hi16(ew);
            wds[s2] = (u32)f2b_bits(flo) | ((u32)f2b_bits(fhi) << 16);
        }
        ff[tt] = make_uint4(wds[0], wds[1], wds[2], wds[3]);
    }

    // ---- out GEMM: k=128, hi+lo split weights -> D to LDS ----
#pragma unroll
    for (int ct = 0; ct < 8; ct++) {
        float bo = w[OFF_BOUT + ct * 16 + j16];
        f32x4 c = {bo, bo, bo, bo};
#pragma unroll
        for (int tt = 0; tt < 4; tt++) {
            c = __builtin_amdgcn_mfma_f32_16x16x32_bf16(*reinterpret_cast<bf16x8*>(&ff[tt]),
                                                        wo_hi[(ct * 4 + tt) * 64 + lane], c, 0, 0, 0);
            c = __builtin_amdgcn_mfma_f32_16x16x32_bf16(*reinterpret_cast<bf16x8*>(&ff[tt]),
                                                        wo_lo[(ct * 4 + tt) * 64 + lane], c, 0, 0, 0);
        }
#pragma unroll
        for (int r = 0; r < 4; r++) g32[g * 4 + r][ct * 16 + j16] = c[r];
    }

    // ---- coalesced store (row it, lane = col pair) ----
    for (int it = 0; it < 16; it++) {
        long rr = row0 + it;
        if (rr >= N_NODES) break;
        float v0 = g32[it][lane * 2], v1 = g32[it][lane * 2 + 1];
        if (isbf) {
            ((u32*)out_b)[rr * 64 + lane] = (u32)f2b_bits(v0) | ((u32)f2b_bits(v1) << 16);
        } else {
            ((float2*)out_f)[rr * 64 + lane] = make_float2(v0, v1);
        }
    }
}

extern "C" void kernel_launch(void* const* d_in, const int* in_sizes, int n_in,
                              void* d_out, int out_size, void* d_ws, size_t ws_size,
                              hipStream_t stream) {
    const void* node_feat = d_in[0];
    const void* edge_feat = d_in[1];
    const int* src = (const int*)d_in[2];
    const int* dst = (const int*)d_in[3];

    // workspace layout (bytes), total ~52.5 MB (proven-safe < 59.6 MB):
    //   0        .. 12.8M : f_src   bf16 [N][128]
    //   12.8M    .. 25.6M : f_dst   bf16 [N][128]  -> edge_max overlays (same [n] slot,
    //                       read-before-write within the owning wave)
    //   32.0M    .. 44.8M : h_node  bf16 [N][128]
    //   44.8M    ..       : deg, rowptr, perm, wcanon(+frags 675KB), flag, rank
    char* ws = (char*)d_ws;
    bf16* f_src = (bf16*)ws;
    bf16* f_dst = (bf16*)(ws + 12800000);
    bf16* edge_max = (bf16*)(ws + 12800000);  // overlays f_dst; node n's wave reads
                                              // f_dst[n] before writing edge_max[n]
    bf16* h_node = (bf16*)(ws + 32000000);
    int* deg = (int*)(ws + 44800000);
    int* rowptr = (int*)(ws + 45000000);
    int* perm = (int*)(ws + 45400016);
    float* wcanon = (float*)(ws + 48600032);  // 168704 floats -> ends 49274848
    int* flag = (int*)(ws + 49274848);
    int* rank = (int*)(ws + 49280000);        // 3.2MB -> ends 52480000

    bf16* out_b = (bf16*)d_out;
    float* out_f = (float*)d_out;
    bf16* out_a_b = out_b + (size_t)N_NODES * OUT_DIM;
    float* out_a_f = out_f + (size_t)N_NODES * OUT_DIM;

    k_init<<<(N_NODES + 255) / 256, 256, 0, stream>>>(node_feat, flag, deg);
    k_prep<<<WCONV_BLOCKS + HIST_BLOCKS, 256, 0, stream>>>(
        d_in[4], d_in[5], d_in[6], d_in[7], d_in[8], d_in[9], d_in[10],
        d_in[11], d_in[12], d_in[13], d_in[14], wcanon, flag, dst, deg, rank);
    k_scan<<<1, 1024, 0, stream>>>(deg, rowptr);
    k_pp<<<PROJ_BLOCKS + HIST_BLOCKS, 256, 0, stream>>>(node_feat, wcanon, flag, f_src, f_dst,
                                                        dst, rowptr, rank, perm);
    k_node_agg<<<N_NODES / 4, 256, 0, stream>>>(rowptr, perm, src, f_src, f_dst, edge_feat,
                                                wcanon, flag, h_node, edge_max, out_a_b, out_a_f);
    k_fuse<<<(N_NODES + 63) / 64, 256, 0, stream>>>(h_node, edge_max, wcanon, flag, out_b, out_f);
}

// Round 13
// 773.608 us; speedup vs baseline: 1.1364x; 1.0089x over previous
//
#include <hip/hip_runtime.h>
#include <hip/hip_bf16.h>

// AdaptiveEdgeGAT: N=50000, E=800000, IN=OUT=128, EDGE=64, H=4, D=32
// CSR (sort-by-dst) + gather-based segmented reductions.
// R1: wave-per-node node_agg. R2: edge-GEMM on MFMA. R4: logits fused in.
// R5: rank-from-atomic hist + atomic-free permute. R6: k_fuse on MFMA.
// R7: k_proj on MFMA. R8: (256,4)/64-VGPR + LDS f_src row cache.
// R9/R10: fat-kernel overlaps + merged node_agg; reg-prefetch reverted (spill).
// R11: (256,5) forced 48 VGPR -> spill. R12: CAPR 24 only — occupancy lever
//      NULL (achieved waves stuck ~38% regardless of theoretical limit).
// R13: TLP levers exhausted -> ILP lever: Phase L gather unroll 4->8
//      (8 loads in flight; addresses all register-derived). VGPR floats to
//      ~80 under the (256,4) 128-cap — floating above 64 is safe, only
//      FORCING below 64 spills (R7/R11 lesson).

#define N_NODES 50000
#define N_EDGES 800000
#define IN_DIM 128
#define OUT_DIM 128
#define EDGE_DIM 64
#define HEADS 4
#define HEAD_DIM 32
#define NEG_SLOPE 0.2f

typedef __hip_bfloat16 bf16;
typedef unsigned short u16;
typedef unsigned int u32;
typedef unsigned long long u64;
typedef __attribute__((ext_vector_type(8))) short bf16x8;
typedef __attribute__((ext_vector_type(4))) float f32x4;

// canonical f32 weight-block offsets (floats)
#define OFF_WSRC 0
#define OFF_BSRC 16384
#define OFF_WDST 16512
#define OFF_BDST 32896
#define OFF_ATTN 33024
#define OFF_WEDGE 33152
#define OFF_BEDGE 41344
#define OFF_WGATE 41472
#define OFF_BGATE 74240
#define OFF_WOUT 74368
#define OFF_BOUT 90752
#define OFF_WEDGE_T 90880   // transposed W_edge: [col][k] = [128][64] (f32, cold path)
#define OFF_WFRAG 99072     // bf16 B-fragments of W_edge^T: 4096 u32 words (16KB)
#define OFF_WFG 103168      // bf16 B-fragments of W_gate: [ct8][tt8][64][4w] = 16384
#define OFF_WFO_HI 119552   // bf16 B-fragments of W_out (hi): [ct8][tt4][64][4w] = 8192
#define OFF_WFO_LO 127744   // bf16 B-fragments of W_out (lo residual): 8192
#define OFF_WFS_HI 135936   // W_src hi fragments: 8192
#define OFF_WFS_LO 144128   // W_src lo fragments: 8192
#define OFF_WFD_HI 152320   // W_dst hi fragments: 8192
#define OFF_WFD_LO 160512   // W_dst lo fragments: 8192
#define W_TOTAL 168704

#define WCONV_BLOCKS 659    // W_TOTAL/256
#define HIST_BLOCKS 3125    // ceil(E/256)
#define PROJ_BLOCKS 782     // ceil(N/64)

__device__ __forceinline__ float b2f_raw(u16 v) {
    return __uint_as_float(((u32)v) << 16);
}
__device__ __forceinline__ float b2f(bf16 v) { return __bfloat162float(v); }
__device__ __forceinline__ float loadin(const void* p, long i, int isbf) {
    return isbf ? b2f_raw(((const u16*)p)[i]) : ((const float*)p)[i];
}
__device__ __forceinline__ float lo16(u32 v) { return __uint_as_float(v << 16); }
__device__ __forceinline__ float hi16(u32 v) { return __uint_as_float(v & 0xFFFF0000u); }
__device__ __forceinline__ u16 f2b_bits(float x) {
    bf16 t = __float2bfloat16(x);
    return *reinterpret_cast<u16*>(&t);
}
// per-col-pair logit partial: leaky_relu(fs + fd) dot attn_w (2 cols of this lane)
__device__ __forceinline__ float logit_part(u32 v, float fdlo, float fdhi, float2 awc) {
    float x0 = lo16(v) + fdlo; x0 = x0 > 0.f ? x0 : NEG_SLOPE * x0;
    float x1 = hi16(v) + fdhi; x1 = x1 > 0.f ? x1 : NEG_SLOPE * x1;
    return x0 * awc.x + x1 * awc.y;
}
// sum across the 16-lane head group
__device__ __forceinline__ float red16(float r) {
    r += __shfl_xor(r, 1); r += __shfl_xor(r, 2);
    r += __shfl_xor(r, 4); r += __shfl_xor(r, 8);
    return r;
}

// ---------- init: dtype detect (block 0) + zero degree counters (all blocks) ----------
__global__ __launch_bounds__(256) void k_init(const void* node, int* flag, int* __restrict__ deg) {
    int i = blockIdx.x * 256 + threadIdx.x;
    if (i < N_NODES) deg[i] = 0;
    if (blockIdx.x == 0) {
        __shared__ int cnt[256];
        int c = 0;
        for (int j = threadIdx.x; j < 8192; j += 256) {
            float v = b2f_raw(((const u16*)node)[j]);
            float a = fabsf(v);
            if ((a >= 1e-4f && a <= 50.f) || v == 0.f) c++;
        }
        cnt[threadIdx.x] = c;
        __syncthreads();
        for (int s = 128; s > 0; s >>= 1) {
            if (threadIdx.x < s) cnt[threadIdx.x] += cnt[threadIdx.x + s];
            __syncthreads();
        }
        if (threadIdx.x == 0) flag[0] = (cnt[0] >= (8192 * 85) / 100) ? 1 : 0;
    }
}

// ---------- fused: weight canonicalization (blocks 0..658) || degree histogram ----------
__global__ __launch_bounds__(256) void k_prep(const void* Wsrc, const void* bsrc,
                                              const void* Wdst, const void* bdst,
                                              const void* attn, const void* Wedge, const void* bedge,
                                              const void* Wgate, const void* bgate,
                                              const void* Wout, const void* bout,
                                              float* w, const int* flag,
                                              const int* __restrict__ dst, int* __restrict__ deg,
                                              int* __restrict__ rank) {
    if (blockIdx.x >= WCONV_BLOCKS) {
        int e = (blockIdx.x - WCONV_BLOCKS) * 256 + threadIdx.x;
        if (e < N_EDGES) rank[e] = atomicAdd(&deg[dst[e]], 1);
        return;
    }
    int i = blockIdx.x * 256 + threadIdx.x;
    if (i >= W_TOTAL) return;
    int f = flag[0];
    const void* p; long off;
    if (i < OFF_BSRC)         { p = Wsrc;  off = i - OFF_WSRC; }
    else if (i < OFF_WDST)    { p = bsrc;  off = i - OFF_BSRC; }
    else if (i < OFF_BDST)    { p = Wdst;  off = i - OFF_WDST; }
    else if (i < OFF_ATTN)    { p = bdst;  off = i - OFF_BDST; }
    else if (i < OFF_WEDGE)   { p = attn;  off = i - OFF_ATTN; }
    else if (i < OFF_BEDGE)   { p = Wedge; off = i - OFF_WEDGE; }
    else if (i < OFF_WGATE)   { p = bedge; off = i - OFF_BEDGE; }
    else if (i < OFF_BGATE)   { p = Wgate; off = i - OFF_WGATE; }
    else if (i < OFF_WOUT)    { p = bgate; off = i - OFF_BGATE; }
    else if (i < OFF_BOUT)    { p = Wout;  off = i - OFF_WOUT; }
    else if (i < OFF_WEDGE_T) { p = bout;  off = i - OFF_BOUT; }
    else if (i < OFF_WFRAG) { // transposed W_edge: wt[col*64+k] = W_edge[k*128+col]
        int idx = i - OFF_WEDGE_T;
        int col = idx >> 6, k = idx & 63;
        w[i] = loadin(Wedge, (long)k * OUT_DIM + col, f);
        return;
    } else if (i < OFF_WFG) {
        // W_edge fragments: wdx = mt*512 + tt*256 + l*4 + s/2 (k in 0..63)
        int wdx = i - OFF_WFRAG;
        int sp = (wdx & 3) * 2;
        int l = (wdx >> 2) & 63;
        int tt = (wdx >> 8) & 1;
        int mt = wdx >> 9;
        int k0 = tt * 32 + ((l >> 4) << 3);
        int col = mt * 16 + (l & 15);
        float v0 = loadin(Wedge, (long)(k0 + sp) * OUT_DIM + col, f);
        float v1 = loadin(Wedge, (long)(k0 + sp + 1) * OUT_DIM + col, f);
        *(u32*)&w[i] = (u32)f2b_bits(v0) | ((u32)f2b_bits(v1) << 16);
        return;
    } else if (i < OFF_WFO_HI) {
        // W_gate fragments: wdx = ct*2048 + tt*256 + l*4 + s/2 (k in 0..255)
        int wdx = i - OFF_WFG;
        int sp = (wdx & 3) * 2;
        int l = (wdx >> 2) & 63;
        int tt = (wdx >> 8) & 7;
        int ct = wdx >> 11;
        int k0 = tt * 32 + ((l >> 4) << 3);
        int c = ct * 16 + (l & 15);
        float v0 = loadin(Wgate, (long)(k0 + sp) * OUT_DIM + c, f);
        float v1 = loadin(Wgate, (long)(k0 + sp + 1) * OUT_DIM + c, f);
        *(u32*)&w[i] = (u32)f2b_bits(v0) | ((u32)f2b_bits(v1) << 16);
        return;
    } else {
        // 128-k matrices (W_out/W_src/W_dst, hi or lo): wdx = ct*1024 + tt*256 + l*4 + s/2
        const void* M; int base; int wantlo;
        if (i < OFF_WFO_LO)      { M = Wout; base = OFF_WFO_HI; wantlo = 0; }
        else if (i < OFF_WFS_HI) { M = Wout; base = OFF_WFO_LO; wantlo = 1; }
        else if (i < OFF_WFS_LO) { M = Wsrc; base = OFF_WFS_HI; wantlo = 0; }
        else if (i < OFF_WFD_HI) { M = Wsrc; base = OFF_WFS_LO; wantlo = 1; }
        else if (i < OFF_WFD_LO) { M = Wdst; base = OFF_WFD_HI; wantlo = 0; }
        else                     { M = Wdst; base = OFF_WFD_LO; wantlo = 1; }
        int wdx = i - base;
        int sp = (wdx & 3) * 2;
        int l = (wdx >> 2) & 63;
        int tt = (wdx >> 8) & 3;
        int ct = wdx >> 10;
        int k0 = tt * 32 + ((l >> 4) << 3);
        int c = ct * 16 + (l & 15);
        float v0 = loadin(M, (long)(k0 + sp) * OUT_DIM + c, f);
        float v1 = loadin(M, (long)(k0 + sp + 1) * OUT_DIM + c, f);
        if (wantlo) {
            v0 = v0 - b2f_raw(f2b_bits(v0));
            v1 = v1 - b2f_raw(f2b_bits(v1));
        }
        *(u32*)&w[i] = (u32)f2b_bits(v0) | ((u32)f2b_bits(v1) << 16);
        return;
    }
    w[i] = loadin(p, off, f);
}

// ---------- exclusive prefix sum: thread-coarsened, 22 barriers total ----------
#define SCAN_CHUNK 49   // 49*1024 = 50176 >= N_NODES
__global__ __launch_bounds__(1024) void k_scan(const int* __restrict__ deg,
                                               int* __restrict__ rowptr) {
    __shared__ int part[1024];
    int tid = threadIdx.x;
    int base = tid * SCAN_CHUNK;
    int s = 0;
    for (int j = 0; j < SCAN_CHUNK; j++) {
        int i = base + j;
        if (i < N_NODES) s += deg[i];
    }
    part[tid] = s;
    __syncthreads();
    for (int st = 1; st < 1024; st <<= 1) {
        int v = (tid >= st) ? part[tid - st] : 0;
        __syncthreads();
        part[tid] += v;
        __syncthreads();
    }
    int run = (tid == 0) ? 0 : part[tid - 1];
    for (int j = 0; j < SCAN_CHUNK; j++) {
        int i = base + j;
        if (i < N_NODES) {
            rowptr[i] = run;
            run += deg[i];
        }
    }
    if (N_NODES >= base && N_NODES < base + SCAN_CHUNK) rowptr[N_NODES] = run;
}

// ---------- fused: node projections on MFMA (blocks 0..781) || edge permute ----------
#define PROJ_PAD 134
__global__ __launch_bounds__(256, 4) void k_pp(const void* __restrict__ node,
                                              const float* __restrict__ w, const int* __restrict__ flag,
                                              bf16* __restrict__ f_src, bf16* __restrict__ f_dst,
                                              const int* __restrict__ dst,
                                              const int* __restrict__ rowptr,
                                              const int* __restrict__ rank,
                                              int* __restrict__ perm) {
    if (blockIdx.x >= PROJ_BLOCKS) {
        int e = (blockIdx.x - PROJ_BLOCKS) * 256 + threadIdx.x;
        if (e < N_EDGES) perm[rowptr[dst[e]] + rank[e]] = e;
        return;
    }
    __shared__ float s_t[4][16][PROJ_PAD];
    const int wv = threadIdx.x >> 6;
    const int lane = threadIdx.x & 63;
    const int g = lane >> 4, j16 = lane & 15;
    const int isbf = flag[0];
    const long row0 = (long)blockIdx.x * 64 + wv * 16;
    if (row0 >= N_NODES) return;
    float (*t32)[PROJ_PAD] = s_t[wv];
    long jr = row0 + j16; if (jr >= N_NODES) jr = N_NODES - 1;

    uint4 ah[4], al[4];
    if (isbf) {
        const uint4* np = (const uint4*)node;
#pragma unroll
        for (int tt = 0; tt < 4; tt++) ah[tt] = np[jr * 16 + tt * 4 + g];
    } else {
        const float4* np = (const float4*)node;
#pragma unroll
        for (int tt = 0; tt < 4; tt++) {
            float4 x0 = np[jr * 32 + tt * 8 + g * 2];
            float4 x1 = np[jr * 32 + tt * 8 + g * 2 + 1];
            float xv[8] = {x0.x, x0.y, x0.z, x0.w, x1.x, x1.y, x1.z, x1.w};
            u32 hw[4], lw[4];
#pragma unroll
            for (int s2 = 0; s2 < 4; s2++) {
                u16 h0 = f2b_bits(xv[s2 * 2]), h1 = f2b_bits(xv[s2 * 2 + 1]);
                float r0 = xv[s2 * 2] - b2f_raw(h0);
                float r1 = xv[s2 * 2 + 1] - b2f_raw(h1);
                hw[s2] = (u32)h0 | ((u32)h1 << 16);
                lw[s2] = (u32)f2b_bits(r0) | ((u32)f2b_bits(r1) << 16);
            }
            ah[tt] = make_uint4(hw[0], hw[1], hw[2], hw[3]);
            al[tt] = make_uint4(lw[0], lw[1], lw[2], lw[3]);
        }
    }

    const bf16x8* wsh = (const bf16x8*)(w + OFF_WFS_HI);
    const bf16x8* wsl = (const bf16x8*)(w + OFF_WFS_LO);
    const bf16x8* wdh = (const bf16x8*)(w + OFF_WFD_HI);
    const bf16x8* wdl = (const bf16x8*)(w + OFF_WFD_LO);

    // ---- f_src = x @ W_src + b ----
#pragma unroll
    for (int ct = 0; ct < 8; ct++) {
        float bs = w[OFF_BSRC + ct * 16 + j16];
        f32x4 c = {bs, bs, bs, bs};
#pragma unroll
        for (int tt = 0; tt < 4; tt++) {
            bf16x8 a = *reinterpret_cast<bf16x8*>(&ah[tt]);
            c = __builtin_amdgcn_mfma_f32_16x16x32_bf16(a, wsh[(ct * 4 + tt) * 64 + lane], c, 0, 0, 0);
            c = __builtin_amdgcn_mfma_f32_16x16x32_bf16(a, wsl[(ct * 4 + tt) * 64 + lane], c, 0, 0, 0);
        }
        if (!isbf) {
#pragma unroll
            for (int tt = 0; tt < 4; tt++)
                c = __builtin_amdgcn_mfma_f32_16x16x32_bf16(*reinterpret_cast<bf16x8*>(&al[tt]),
                                                            wsh[(ct * 4 + tt) * 64 + lane], c, 0, 0, 0);
        }
#pragma unroll
        for (int r = 0; r < 4; r++) t32[g * 4 + r][ct * 16 + j16] = c[r];
    }
    for (int it = 0; it < 16; it++) {
        long rr = row0 + it;
        if (rr >= N_NODES) break;
        ((u32*)f_src)[rr * 64 + lane] =
            (u32)f2b_bits(t32[it][lane * 2]) | ((u32)f2b_bits(t32[it][lane * 2 + 1]) << 16);
    }

    // ---- f_dst = x @ W_dst + b ----
#pragma unroll
    for (int ct = 0; ct < 8; ct++) {
        float bd = w[OFF_BDST + ct * 16 + j16];
        f32x4 c = {bd, bd, bd, bd};
#pragma unroll
        for (int tt = 0; tt < 4; tt++) {
            bf16x8 a = *reinterpret_cast<bf16x8*>(&ah[tt]);
            c = __builtin_amdgcn_mfma_f32_16x16x32_bf16(a, wdh[(ct * 4 + tt) * 64 + lane], c, 0, 0, 0);
            c = __builtin_amdgcn_mfma_f32_16x16x32_bf16(a, wdl[(ct * 4 + tt) * 64 + lane], c, 0, 0, 0);
        }
        if (!isbf) {
#pragma unroll
            for (int tt = 0; tt < 4; tt++)
                c = __builtin_amdgcn_mfma_f32_16x16x32_bf16(*reinterpret_cast<bf16x8*>(&al[tt]),
                                                            wdh[(ct * 4 + tt) * 64 + lane], c, 0, 0, 0);
        }
#pragma unroll
        for (int r = 0; r < 4; r++) t32[g * 4 + r][ct * 16 + j16] = c[r];
    }
    for (int it = 0; it < 16; it++) {
        long rr = row0 + it;
        if (rr >= N_NODES) break;
        ((u32*)f_dst)[rr * 64 + lane] =
            (u32)f2b_bits(t32[it][lane * 2]) | ((u32)f2b_bits(t32[it][lane * 2 + 1]) << 16);
    }
}

// ---------- per-node aggregation: wave-per-node, fused logits+softmax+agg ----------
// All LDS wave-private -> zero barriers. Single dispatch.
// R13: Phase L gather unroll 8 (8 loads in flight). launch_bounds(256,4) so
// VGPR floats (~80) — floating above 64 is safe; forcing below 64 spills.
#define CAPR 24   // cached f_src rows per node (P(deg>24)~2% re-gathers L2-warm)
__global__ __launch_bounds__(256, 4) void k_node_agg(const int* __restrict__ rowptr,
                                                  const int* __restrict__ perm,
                                                  const int* __restrict__ src,
                                                  const bf16* __restrict__ f_src,
                                                  const bf16* __restrict__ f_dst,
                                                  const void* __restrict__ edge_feat,
                                                  const float* __restrict__ w, const int* __restrict__ flag,
                                                  bf16* __restrict__ h_node, bf16* __restrict__ edge_max,
                                                  bf16* __restrict__ out_a_b, float* __restrict__ out_a_f) {
    __shared__ int s_esrc[4][64];
    __shared__ __align__(16) float s_a[4][64][4];
    __shared__ __align__(16) float s_vmax[4][128];
    __shared__ u32 s_xs[4][CAPR][64];   // cached f_src rows (u32 = 2 bf16 cols/lane)

    const int wv = threadIdx.x >> 6;
    const int lane = threadIdx.x & 63;
    const int n = blockIdx.x * 4 + wv;
    const int isbf = flag[0];
    const int r0 = rowptr[n], r1 = rowptr[n + 1];
    const int deg = r1 - r0;

    int* esrc = s_esrc[wv];
    float (*aA)[4] = s_a[wv];
    float* vm = s_vmax[wv];
    u32 (*xs)[64] = s_xs[wv];

    const u32* fs32 = (const u32*)f_src;
    const int g = lane >> 4;          // head group of this lane's column pair
    const int dm = deg < 64 ? deg : 64;

    // ---- Phase 1: per-lane edge metadata ----
    int e0 = 0, sv = 0;
    if (lane < deg) {
        e0 = perm[r0 + lane];
        sv = src[e0];
        esrc[lane] = sv;
    }

    // ---- Phase L: fused GATv2 logits (+ row cache fill), 8 gathers in flight ----
    u32 fdw = ((const u32*)f_dst)[(long)n * 64 + lane];
    const float fdlo = lo16(fdw), fdhi = hi16(fdw);
    const float2 awc = *(const float2*)&w[OFF_ATTN + lane * 2];
    {
        int j = 0;
        for (; j + 8 <= dm; j += 8) {
            int sA = __shfl(sv, j),     sB = __shfl(sv, j + 1);
            int sC = __shfl(sv, j + 2), sD = __shfl(sv, j + 3);
            int sE = __shfl(sv, j + 4), sF = __shfl(sv, j + 5);
            int sG = __shfl(sv, j + 6), sH = __shfl(sv, j + 7);
            u32 vA = fs32[(long)sA * 64 + lane];
            u32 vB = fs32[(long)sB * 64 + lane];
            u32 vC = fs32[(long)sC * 64 + lane];
            u32 vD = fs32[(long)sD * 64 + lane];
            u32 vE = fs32[(long)sE * 64 + lane];
            u32 vF = fs32[(long)sF * 64 + lane];
            u32 vG = fs32[(long)sG * 64 + lane];
            u32 vH = fs32[(long)sH * 64 + lane];
            if (j + 7 < CAPR) {   // CAPR multiple of 8
                xs[j][lane] = vA;     xs[j + 1][lane] = vB;
                xs[j + 2][lane] = vC; xs[j + 3][lane] = vD;
                xs[j + 4][lane] = vE; xs[j + 5][lane] = vF;
                xs[j + 6][lane] = vG; xs[j + 7][lane] = vH;
            }
            float rA = red16(logit_part(vA, fdlo, fdhi, awc));
            float rB = red16(logit_part(vB, fdlo, fdhi, awc));
            float rC = red16(logit_part(vC, fdlo, fdhi, awc));
            float rD = red16(logit_part(vD, fdlo, fdhi, awc));
            float rE = red16(logit_part(vE, fdlo, fdhi, awc));
            float rF = red16(logit_part(vF, fdlo, fdhi, awc));
            float rG = red16(logit_part(vG, fdlo, fdhi, awc));
            float rH = red16(logit_part(vH, fdlo, fdhi, awc));
            if ((lane & 15) == 0) {
                aA[j][g] = rA;     aA[j + 1][g] = rB;
                aA[j + 2][g] = rC; aA[j + 3][g] = rD;
                aA[j + 4][g] = rE; aA[j + 5][g] = rF;
                aA[j + 6][g] = rG; aA[j + 7][g] = rH;
            }
        }
        for (; j + 4 <= dm; j += 4) {
            int sA = __shfl(sv, j), sB = __shfl(sv, j + 1);
            int sC = __shfl(sv, j + 2), sD = __shfl(sv, j + 3);
            u32 vA = fs32[(long)sA * 64 + lane];
            u32 vB = fs32[(long)sB * 64 + lane];
            u32 vC = fs32[(long)sC * 64 + lane];
            u32 vD = fs32[(long)sD * 64 + lane];
            if (j + 3 < CAPR) {
                xs[j][lane] = vA; xs[j + 1][lane] = vB;
                xs[j + 2][lane] = vC; xs[j + 3][lane] = vD;
            }
            float rA = red16(logit_part(vA, fdlo, fdhi, awc));
            float rB = red16(logit_part(vB, fdlo, fdhi, awc));
            float rC = red16(logit_part(vC, fdlo, fdhi, awc));
            float rD = red16(logit_part(vD, fdlo, fdhi, awc));
            if ((lane & 15) == 0) {
                aA[j][g] = rA; aA[j + 1][g] = rB;
                aA[j + 2][g] = rC; aA[j + 3][g] = rD;
            }
        }
        for (; j < dm; j++) {
            int sA = __shfl(sv, j);
            u32 vA = fs32[(long)sA * 64 + lane];
            if (j < CAPR) xs[j][lane] = vA;
            float rA = red16(logit_part(vA, fdlo, fdhi, awc));
            if ((lane & 15) == 0) aA[j][g] = rA;
        }
    }

    // ---- Phase 2: softmax in registers (lane j owns edge j) ----
    float l0 = -3.0e38f, l1 = -3.0e38f, l2 = -3.0e38f, l3 = -3.0e38f;
    if (lane < deg) {
        float4 lv = *(float4*)aA[lane];
        l0 = lv.x; l1 = lv.y; l2 = lv.z; l3 = lv.w;
    }
    float m0 = l0, m1 = l1, m2 = l2, m3 = l3;
#pragma unroll
    for (int s = 1; s < 64; s <<= 1) {
        m0 = fmaxf(m0, __shfl_xor(m0, s));
        m1 = fmaxf(m1, __shfl_xor(m1, s));
        m2 = fmaxf(m2, __shfl_xor(m2, s));
        m3 = fmaxf(m3, __shfl_xor(m3, s));
    }
    for (int jj = 64; jj < deg; jj++) {   // cold: deg > 64 — cooperative logit, max
        int e = perm[r0 + jj];
        int s0 = src[e];
        u32 v = fs32[(long)s0 * 64 + lane];
        float red = red16(logit_part(v, fdlo, fdhi, awc));
        float q0 = __shfl(red, 0), q1 = __shfl(red, 16);
        float q2 = __shfl(red, 32), q3 = __shfl(red, 48);
        m0 = fmaxf(m0, q0); m1 = fmaxf(m1, q1);
        m2 = fmaxf(m2, q2); m3 = fmaxf(m3, q3);
    }
    float p0 = 0.f, p1 = 0.f, p2 = 0.f, p3 = 0.f;
    if (lane < deg) {
        p0 = __expf(l0 - m0); p1 = __expf(l1 - m1);
        p2 = __expf(l2 - m2); p3 = __expf(l3 - m3);
    }
    float t0 = p0, t1 = p1, t2 = p2, t3 = p3;
#pragma unroll
    for (int s = 1; s < 64; s <<= 1) {
        t0 += __shfl_xor(t0, s);
        t1 += __shfl_xor(t1, s);
        t2 += __shfl_xor(t2, s);
        t3 += __shfl_xor(t3, s);
    }
    for (int jj = 64; jj < deg; jj++) {   // cold: sum of overflow exps (uniform)
        int e = perm[r0 + jj];
        int s0 = src[e];
        u32 v = fs32[(long)s0 * 64 + lane];
        float red = red16(logit_part(v, fdlo, fdhi, awc));
        t0 += __expf(__shfl(red, 0) - m0);
        t1 += __expf(__shfl(red, 16) - m1);
        t2 += __expf(__shfl(red, 32) - m2);
        t3 += __expf(__shfl(red, 48) - m3);
    }
    const float i0 = 1.f / fmaxf(t0, 1e-9f);
    const float i1 = 1.f / fmaxf(t1, 1e-9f);
    const float i2 = 1.f / fmaxf(t2, 1e-9f);
    const float i3 = 1.f / fmaxf(t3, 1e-9f);
    if (lane < deg) {
        float a0 = p0 * i0, a1 = p1 * i1, a2 = p2 * i2, a3 = p3 * i3;
        *(float4*)aA[lane] = make_float4(a0, a1, a2, a3);
        if (isbf) {
            u64 pk = (u64)f2b_bits(a0) | ((u64)f2b_bits(a1) << 16)
                   | ((u64)f2b_bits(a2) << 32) | ((u64)f2b_bits(a3) << 48);
            ((u64*)out_a_b)[e0] = pk;
        } else {
            ((float4*)out_a_f)[e0] = make_float4(a0, a1, a2, a3);
        }
    }

    // ---- Phase 3a: message accumulate — cached rows from LDS, rest from global ----
    const int hsel = g;
    float acc0 = 0.f, acc1 = 0.f;
    const int capn = dm < CAPR ? dm : CAPR;
    int j = 0;
    for (; j + 4 <= capn; j += 4) {
        float a0 = aA[j][hsel], a1 = aA[j + 1][hsel];
        float a2 = aA[j + 2][hsel], a3 = aA[j + 3][hsel];
        u32 v0 = xs[j][lane];
        u32 v1 = xs[j + 1][lane];
        u32 v2 = xs[j + 2][lane];
        u32 v3 = xs[j + 3][lane];
        acc0 += lo16(v0) * a0 + lo16(v1) * a1 + lo16(v2) * a2 + lo16(v3) * a3;
        acc1 += hi16(v0) * a0 + hi16(v1) * a1 + hi16(v2) * a2 + hi16(v3) * a3;
    }
    for (; j < capn; j++) {
        float a0 = aA[j][hsel];
        u32 v0 = xs[j][lane];
        acc0 += lo16(v0) * a0;
        acc1 += hi16(v0) * a0;
    }
    for (; j < dm; j++) {   // deg in (CAPR,64]: re-gather (L2-warm)
        int s0 = esrc[j];
        float a0 = aA[j][hsel];
        u32 v0 = fs32[(long)s0 * 64 + lane];
        acc0 += lo16(v0) * a0;
        acc1 += hi16(v0) * a0;
    }
    if (deg > 64) {   // cold: cooperative logit -> a -> out_a + message
        float mh = (hsel & 2) ? ((hsel & 1) ? m3 : m2) : ((hsel & 1) ? m1 : m0);
        float ih = (hsel & 2) ? ((hsel & 1) ? i3 : i2) : ((hsel & 1) ? i1 : i0);
        for (int jj = 64; jj < deg; jj++) {
            int e = perm[r0 + jj];
            int s0 = src[e];
            u32 v = fs32[(long)s0 * 64 + lane];
            float red = red16(logit_part(v, fdlo, fdhi, awc));
            float q0 = __shfl(red, 0), q1 = __shfl(red, 16);
            float q2 = __shfl(red, 32), q3 = __shfl(red, 48);
            float a0 = __expf(q0 - m0) * i0, a1 = __expf(q1 - m1) * i1;
            float a2 = __expf(q2 - m2) * i2, a3 = __expf(q3 - m3) * i3;
            if (lane == 0) {
                if (isbf) {
                    u64 pk = (u64)f2b_bits(a0) | ((u64)f2b_bits(a1) << 16)
                           | ((u64)f2b_bits(a2) << 32) | ((u64)f2b_bits(a3) << 48);
                    ((u64*)out_a_b)[e] = pk;
                } else {
                    ((float4*)out_a_f)[e] = make_float4(a0, a1, a2, a3);
                }
            }
            float qh = (hsel & 2) ? ((hsel & 1) ? q3 : q2) : ((hsel & 1) ? q1 : q0);
            float ah = __expf(qh - mh) * ih;
            acc0 += lo16(v) * ah;
            acc1 += hi16(v) * ah;
        }
    }
    ((u32*)h_node)[n * 64 + lane] =
        (u32)f2b_bits(acc0) | ((u32)f2b_bits(acc1) << 16);

    // ---- Phase 3b: edge encoder GEMM on MFMA + column max ----
    if (deg == 0) {
        ((u32*)edge_max)[(long)n * 64 + lane] = 0u;
        return;
    }
    {
        const bf16x8* wfb = (const bf16x8*)(w + OFF_WFRAG);
        const int ntiles = deg >= 64 ? 4 : ((deg + 15) >> 4);
        for (int nt = 0; nt < ntiles; nt++) {
            const int je = nt * 16 + (lane & 15);
            const int ej = __shfl(e0, je);      // e0 defaults 0 for pad lanes (masked below)
            bf16x8 bf0, bf1;
            if (isbf) {
                const uint4* ef = (const uint4*)edge_feat;
                uint4 q0 = ef[(long)ej * 8 + g];
                uint4 q1 = ef[(long)ej * 8 + 4 + g];
                bf0 = *reinterpret_cast<bf16x8*>(&q0);
                bf1 = *reinterpret_cast<bf16x8*>(&q1);
            } else {
                const float4* ef = (const float4*)edge_feat;
                long base = (long)ej * 16 + g * 2;
                float4 x0 = ef[base], x1 = ef[base + 1];
                float4 y0 = ef[base + 8], y1 = ef[base + 9];
                bf0[0] = (short)f2b_bits(x0.x); bf0[1] = (short)f2b_bits(x0.y);
                bf0[2] = (short)f2b_bits(x0.z); bf0[3] = (short)f2b_bits(x0.w);
                bf0[4] = (short)f2b_bits(x1.x); bf0[5] = (short)f2b_bits(x1.y);
                bf0[6] = (short)f2b_bits(x1.z); bf0[7] = (short)f2b_bits(x1.w);
                bf1[0] = (short)f2b_bits(y0.x); bf1[1] = (short)f2b_bits(y0.y);
                bf1[2] = (short)f2b_bits(y0.z); bf1[3] = (short)f2b_bits(y0.w);
                bf1[4] = (short)f2b_bits(y1.x); bf1[5] = (short)f2b_bits(y1.y);
                bf1[6] = (short)f2b_bits(y1.z); bf1[7] = (short)f2b_bits(y1.w);
            }
            const bool valid = je < deg;
#pragma unroll
            for (int mt = 0; mt < 8; mt++) {
                float4 b4 = *(const float4*)(w + OFF_BEDGE + mt * 16 + g * 4);
                f32x4 c = {b4.x, b4.y, b4.z, b4.w};   // bias rides in C-init
                c = __builtin_amdgcn_mfma_f32_16x16x32_bf16(wfb[(mt * 2 + 0) * 64 + lane], bf0, c, 0, 0, 0);
                c = __builtin_amdgcn_mfma_f32_16x16x32_bf16(wfb[(mt * 2 + 1) * 64 + lane], bf1, c, 0, 0, 0);
                float v0 = c[0], v1 = c[1], v2 = c[2], v3 = c[3];
                v0 = v0 > 0.f ? v0 : __expf(v0) - 1.f;
                v1 = v1 > 0.f ? v1 : __expf(v1) - 1.f;
                v2 = v2 > 0.f ? v2 : __expf(v2) - 1.f;
                v3 = v3 > 0.f ? v3 : __expf(v3) - 1.f;
                if (!valid) { v0 = v1 = v2 = v3 = -3.0e38f; }
#pragma unroll
                for (int mm = 1; mm < 16; mm <<= 1) {
                    v0 = fmaxf(v0, __shfl_xor(v0, mm));
                    v1 = fmaxf(v1, __shfl_xor(v1, mm));
                    v2 = fmaxf(v2, __shfl_xor(v2, mm));
                    v3 = fmaxf(v3, __shfl_xor(v3, mm));
                }
                if ((lane & 15) == 0) {
                    float4* vp = (float4*)&vm[mt * 16 + g * 4];
                    if (nt == 0) {
                        *vp = make_float4(v0, v1, v2, v3);
                    } else {
                        float4 o = *vp;
                        *vp = make_float4(fmaxf(o.x, v0), fmaxf(o.y, v1),
                                          fmaxf(o.z, v2), fmaxf(o.w, v3));
                    }
                }
            }
        }
        if (deg > 64) {   // ultra-cold overflow: scalar per-column path
            for (int jj = 64; jj < deg; jj++) {
                long e = perm[r0 + jj];
#pragma unroll 1
                for (int p = 0; p < 2; p++) {
                    int col = lane + p * 64;
                    const float4* wt4 = (const float4*)(w + OFF_WEDGE_T + col * EDGE_DIM);
                    float acc = w[OFF_BEDGE + col];
                    for (int kk = 0; kk < 16; kk++) {
                        float4 wv4 = wt4[kk];
                        float xx, xy, xz, xw;
                        if (isbf) {
                            u64 q = ((const u64*)edge_feat)[e * 16 + kk];
                            xx = b2f_raw((u16)q); xy = b2f_raw((u16)(q >> 16));
                            xz = b2f_raw((u16)(q >> 32)); xw = b2f_raw((u16)(q >> 48));
                        } else {
                            float4 xf = ((const float4*)edge_feat)[e * 16 + kk];
                            xx = xf.x; xy = xf.y; xz = xf.z; xw = xf.w;
                        }
                        acc += xx * wv4.x + xy * wv4.y + xz * wv4.z + xw * wv4.w;
                    }
                    float el = acc > 0.f ? acc : __expf(acc) - 1.f;
                    vm[col] = fmaxf(vm[col], el);
                }
            }
        }
        float2 vv = *(float2*)&vm[lane * 2];
        ((u32*)edge_max)[(long)n * 64 + lane] =
            (u32)f2b_bits(vv.x) | ((u32)f2b_bits(vv.y) << 16);
    }
}

// ---------- fused gate + output projection on MFMA ----------
#define FUSE_PAD 134
__global__ __launch_bounds__(256, 4) void k_fuse(const bf16* __restrict__ h_node,
                                              const bf16* __restrict__ edge_max,
                                              const float* __restrict__ w, const int* __restrict__ flag,
                                              bf16* __restrict__ out_b, float* __restrict__ out_f) {
    __shared__ float s_g[4][16][FUSE_PAD];
    const int wv = threadIdx.x >> 6;
    const int lane = threadIdx.x & 63;
    const int g = lane >> 4, j16 = lane & 15;
    const int isbf = flag[0];
    const long row0 = (long)blockIdx.x * 64 + wv * 16;
    if (row0 >= N_NODES) return;
    float (*g32)[FUSE_PAD] = s_g[wv];

    long jr = row0 + j16; if (jr >= N_NODES) jr = N_NODES - 1;
    uint4 hnf[4], emf[4];
    const uint4* hp = (const uint4*)h_node;
    const uint4* ep = (const uint4*)edge_max;
#pragma unroll
    for (int tt = 0; tt < 4; tt++) {
        hnf[tt] = hp[jr * 16 + tt * 4 + g];
        emf[tt] = ep[jr * 16 + tt * 4 + g];
    }
    const bf16x8* wg = (const bf16x8*)(w + OFF_WFG);
    const bf16x8* wo_hi = (const bf16x8*)(w + OFF_WFO_HI);
    const bf16x8* wo_lo = (const bf16x8*)(w + OFF_WFO_LO);

    // ---- gate GEMM: k=256 (hn: tt0-3, em: tt4-7) -> logits to LDS ----
#pragma unroll
    for (int ct = 0; ct < 8; ct++) {
        float bg = w[OFF_BGATE + ct * 16 + j16];
        f32x4 c = {bg, bg, bg, bg};
#pragma unroll
        for (int tt = 0; tt < 4; tt++)
            c = __builtin_amdgcn_mfma_f32_16x16x32_bf16(*reinterpret_cast<bf16x8*>(&hnf[tt]),
                                                        wg[(ct * 8 + tt) * 64 + lane], c, 0, 0, 0);
#pragma unroll
        for (int tt = 0; tt < 4; tt++)
            c = __builtin_amdgcn_mfma_f32_16x16x32_bf16(*reinterpret_cast<bf16x8*>(&emf[tt]),
                                                        wg[(ct * 8 + 4 + tt) * 64 + lane], c, 0, 0, 0);
#pragma unroll
        for (int r = 0; r < 4; r++) g32[g * 4 + r][ct * 16 + j16] = c[r];
    }

    // ---- fused bf16 A-frags: sigmoid(gate) combined with register hn/em ----
    uint4 ff[4];
#pragma unroll
    for (int tt = 0; tt < 4; tt++) {
        u32 wds[4];
        const float* gr = &g32[j16][tt * 32 + 8 * g];
#pragma unroll
        for (int s2 = 0; s2 < 4; s2++) {
            float glo = gr[s2 * 2], ghi = gr[s2 * 2 + 1];
            u32 hw = ((const u32*)&hnf[tt])[s2];
            u32 ew = ((const u32*)&emf[tt])[s2];
            float slo = 1.f / (1.f + __expf(-glo));
            float shi = 1.f / (1.f + __expf(-ghi));
            float flo = slo * lo16(hw) + (1.f - slo) * lo16(ew);
            float fhi = shi * hi16(hw) + (1.f - shi) * hi16(ew);
            wds[s2] = (u32)f2b_bits(flo) | ((u32)f2b_bits(fhi) << 16);
        }
        ff[tt] = make_uint4(wds[0], wds[1], wds[2], wds[3]);
    }

    // ---- out GEMM: k=128, hi+lo split weights -> D to LDS ----
#pragma unroll
    for (int ct = 0; ct < 8; ct++) {
        float bo = w[OFF_BOUT + ct * 16 + j16];
        f32x4 c = {bo, bo, bo, bo};
#pragma unroll
        for (int tt = 0; tt < 4; tt++) {
            c = __builtin_amdgcn_mfma_f32_16x16x32_bf16(*reinterpret_cast<bf16x8*>(&ff[tt]),
                                                        wo_hi[(ct * 4 + tt) * 64 + lane], c, 0, 0, 0);
            c = __builtin_amdgcn_mfma_f32_16x16x32_bf16(*reinterpret_cast<bf16x8*>(&ff[tt]),
                                                        wo_lo[(ct * 4 + tt) * 64 + lane], c, 0, 0, 0);
        }
#pragma unroll
        for (int r = 0; r < 4; r++) g32[g * 4 + r][ct * 16 + j16] = c[r];
    }

    // ---- coalesced store (row it, lane = col pair) ----
    for (int it = 0; it < 16; it++) {
        long rr = row0 + it;
        if (rr >= N_NODES) break;
        float v0 = g32[it][lane * 2], v1 = g32[it][lane * 2 + 1];
        if (isbf) {
            ((u32*)out_b)[rr * 64 + lane] = (u32)f2b_bits(v0) | ((u32)f2b_bits(v1) << 16);
        } else {
            ((float2*)out_f)[rr * 64 + lane] = make_float2(v0, v1);
        }
    }
}

extern "C" void kernel_launch(void* const* d_in, const int* in_sizes, int n_in,
                              void* d_out, int out_size, void* d_ws, size_t ws_size,
                              hipStream_t stream) {
    const void* node_feat = d_in[0];
    const void* edge_feat = d_in[1];
    const int* src = (const int*)d_in[2];
    const int* dst = (const int*)d_in[3];

    // workspace layout (bytes), total ~52.5 MB (proven-safe < 59.6 MB):
    //   0        .. 12.8M : f_src   bf16 [N][128]
    //   12.8M    .. 25.6M : f_dst   bf16 [N][128]  -> edge_max overlays (same [n] slot,
    //                       read-before-write within the owning wave)
    //   32.0M    .. 44.8M : h_node  bf16 [N][128]
    //   44.8M    ..       : deg, rowptr, perm, wcanon(+frags 675KB), flag, rank
    char* ws = (char*)d_ws;
    bf16* f_src = (bf16*)ws;
    bf16* f_dst = (bf16*)(ws + 12800000);
    bf16* edge_max = (bf16*)(ws + 12800000);  // overlays f_dst; node n's wave reads
                                              // f_dst[n] before writing edge_max[n]
    bf16* h_node = (bf16*)(ws + 32000000);
    int* deg = (int*)(ws + 44800000);
    int* rowptr = (int*)(ws + 45000000);
    int* perm = (int*)(ws + 45400016);
    float* wcanon = (float*)(ws + 48600032);  // 168704 floats -> ends 49274848
    int* flag = (int*)(ws + 49274848);
    int* rank = (int*)(ws + 49280000);        // 3.2MB -> ends 52480000

    bf16* out_b = (bf16*)d_out;
    float* out_f = (float*)d_out;
    bf16* out_a_b = out_b + (size_t)N_NODES * OUT_DIM;
    float* out_a_f = out_f + (size_t)N_NODES * OUT_DIM;

    k_init<<<(N_NODES + 255) / 256, 256, 0, stream>>>(node_feat, flag, deg);
    k_prep<<<WCONV_BLOCKS + HIST_BLOCKS, 256, 0, stream>>>(
        d_in[4], d_in[5], d_in[6], d_in[7], d_in[8], d_in[9], d_in[10],
        d_in[11], d_in[12], d_in[13], d_in[14], wcanon, flag, dst, deg, rank);
    k_scan<<<1, 1024, 0, stream>>>(deg, rowptr);
    k_pp<<<PROJ_BLOCKS + HIST_BLOCKS, 256, 0, stream>>>(node_feat, wcanon, flag, f_src, f_dst,
                                                        dst, rowptr, rank, perm);
    k_node_agg<<<N_NODES / 4, 256, 0, stream>>>(rowptr, perm, src, f_src, f_dst, edge_feat,
                                                wcanon, flag, h_node, edge_max, out_a_b, out_a_f);
    k_fuse<<<(N_NODES + 63) / 64, 256, 0, stream>>>(h_node, edge_max, wcanon, flag, out_b, out_f);
}

// Round 14
// 763.043 us; speedup vs baseline: 1.1521x; 1.0138x over previous
//
#include <hip/hip_runtime.h>
#include <hip/hip_bf16.h>

// AdaptiveEdgeGAT: N=50000, E=800000, IN=OUT=128, EDGE=64, H=4, D=32
// CSR (sort-by-dst) + gather-based segmented reductions.
// R1: wave-per-node node_agg. R2: edge-GEMM on MFMA. R4: logits fused in.
// R5: rank-from-atomic hist + atomic-free permute. R6: k_fuse on MFMA.
// R7: k_proj on MFMA. R8: (256,4)/64-VGPR + LDS f_src row cache.
// R9/R10: fat-kernel overlaps + merged node_agg; whole-kernel reg-prefetch
//      spilled (32 VGPR held everywhere). R11: forced 48 VGPR -> spill.
// R12: CAPR 24 (occupancy null -> latency-bound confirmed). R13: Phase L
//      unroll 8 (-10us; gathers mostly L2-hit).
// R14: tile-0 edge_feat prefetch with SHORT live range (issued after Phase L,
//      consumed in 3b; held only across Phase 2+3a softmax/LDS work ~900cy).
//      8 VGPRs short-span vs R9's 32 whole-kernel — spill tripwire: WRITE_SIZE.

#define N_NODES 50000
#define N_EDGES 800000
#define IN_DIM 128
#define OUT_DIM 128
#define EDGE_DIM 64
#define HEADS 4
#define HEAD_DIM 32
#define NEG_SLOPE 0.2f

typedef __hip_bfloat16 bf16;
typedef unsigned short u16;
typedef unsigned int u32;
typedef unsigned long long u64;
typedef __attribute__((ext_vector_type(8))) short bf16x8;
typedef __attribute__((ext_vector_type(4))) float f32x4;

// canonical f32 weight-block offsets (floats)
#define OFF_WSRC 0
#define OFF_BSRC 16384
#define OFF_WDST 16512
#define OFF_BDST 32896
#define OFF_ATTN 33024
#define OFF_WEDGE 33152
#define OFF_BEDGE 41344
#define OFF_WGATE 41472
#define OFF_BGATE 74240
#define OFF_WOUT 74368
#define OFF_BOUT 90752
#define OFF_WEDGE_T 90880   // transposed W_edge: [col][k] = [128][64] (f32, cold path)
#define OFF_WFRAG 99072     // bf16 B-fragments of W_edge^T: 4096 u32 words (16KB)
#define OFF_WFG 103168      // bf16 B-fragments of W_gate: [ct8][tt8][64][4w] = 16384
#define OFF_WFO_HI 119552   // bf16 B-fragments of W_out (hi): [ct8][tt4][64][4w] = 8192
#define OFF_WFO_LO 127744   // bf16 B-fragments of W_out (lo residual): 8192
#define OFF_WFS_HI 135936   // W_src hi fragments: 8192
#define OFF_WFS_LO 144128   // W_src lo fragments: 8192
#define OFF_WFD_HI 152320   // W_dst hi fragments: 8192
#define OFF_WFD_LO 160512   // W_dst lo fragments: 8192
#define W_TOTAL 168704

#define WCONV_BLOCKS 659    // W_TOTAL/256
#define HIST_BLOCKS 3125    // ceil(E/256)
#define PROJ_BLOCKS 782     // ceil(N/64)

__device__ __forceinline__ float b2f_raw(u16 v) {
    return __uint_as_float(((u32)v) << 16);
}
__device__ __forceinline__ float b2f(bf16 v) { return __bfloat162float(v); }
__device__ __forceinline__ float loadin(const void* p, long i, int isbf) {
    return isbf ? b2f_raw(((const u16*)p)[i]) : ((const float*)p)[i];
}
__device__ __forceinline__ float lo16(u32 v) { return __uint_as_float(v << 16); }
__device__ __forceinline__ float hi16(u32 v) { return __uint_as_float(v & 0xFFFF0000u); }
__device__ __forceinline__ u16 f2b_bits(float x) {
    bf16 t = __float2bfloat16(x);
    return *reinterpret_cast<u16*>(&t);
}
// per-col-pair logit partial: leaky_relu(fs + fd) dot attn_w (2 cols of this lane)
__device__ __forceinline__ float logit_part(u32 v, float fdlo, float fdhi, float2 awc) {
    float x0 = lo16(v) + fdlo; x0 = x0 > 0.f ? x0 : NEG_SLOPE * x0;
    float x1 = hi16(v) + fdhi; x1 = x1 > 0.f ? x1 : NEG_SLOPE * x1;
    return x0 * awc.x + x1 * awc.y;
}
// sum across the 16-lane head group
__device__ __forceinline__ float red16(float r) {
    r += __shfl_xor(r, 1); r += __shfl_xor(r, 2);
    r += __shfl_xor(r, 4); r += __shfl_xor(r, 8);
    return r;
}

// ---------- init: dtype detect (block 0) + zero degree counters (all blocks) ----------
__global__ __launch_bounds__(256) void k_init(const void* node, int* flag, int* __restrict__ deg) {
    int i = blockIdx.x * 256 + threadIdx.x;
    if (i < N_NODES) deg[i] = 0;
    if (blockIdx.x == 0) {
        __shared__ int cnt[256];
        int c = 0;
        for (int j = threadIdx.x; j < 8192; j += 256) {
            float v = b2f_raw(((const u16*)node)[j]);
            float a = fabsf(v);
            if ((a >= 1e-4f && a <= 50.f) || v == 0.f) c++;
        }
        cnt[threadIdx.x] = c;
        __syncthreads();
        for (int s = 128; s > 0; s >>= 1) {
            if (threadIdx.x < s) cnt[threadIdx.x] += cnt[threadIdx.x + s];
            __syncthreads();
        }
        if (threadIdx.x == 0) flag[0] = (cnt[0] >= (8192 * 85) / 100) ? 1 : 0;
    }
}

// ---------- fused: weight canonicalization (blocks 0..658) || degree histogram ----------
__global__ __launch_bounds__(256) void k_prep(const void* Wsrc, const void* bsrc,
                                              const void* Wdst, const void* bdst,
                                              const void* attn, const void* Wedge, const void* bedge,
                                              const void* Wgate, const void* bgate,
                                              const void* Wout, const void* bout,
                                              float* w, const int* flag,
                                              const int* __restrict__ dst, int* __restrict__ deg,
                                              int* __restrict__ rank) {
    if (blockIdx.x >= WCONV_BLOCKS) {
        int e = (blockIdx.x - WCONV_BLOCKS) * 256 + threadIdx.x;
        if (e < N_EDGES) rank[e] = atomicAdd(&deg[dst[e]], 1);
        return;
    }
    int i = blockIdx.x * 256 + threadIdx.x;
    if (i >= W_TOTAL) return;
    int f = flag[0];
    const void* p; long off;
    if (i < OFF_BSRC)         { p = Wsrc;  off = i - OFF_WSRC; }
    else if (i < OFF_WDST)    { p = bsrc;  off = i - OFF_BSRC; }
    else if (i < OFF_BDST)    { p = Wdst;  off = i - OFF_WDST; }
    else if (i < OFF_ATTN)    { p = bdst;  off = i - OFF_BDST; }
    else if (i < OFF_WEDGE)   { p = attn;  off = i - OFF_ATTN; }
    else if (i < OFF_BEDGE)   { p = Wedge; off = i - OFF_WEDGE; }
    else if (i < OFF_WGATE)   { p = bedge; off = i - OFF_BEDGE; }
    else if (i < OFF_BGATE)   { p = Wgate; off = i - OFF_WGATE; }
    else if (i < OFF_WOUT)    { p = bgate; off = i - OFF_BGATE; }
    else if (i < OFF_BOUT)    { p = Wout;  off = i - OFF_WOUT; }
    else if (i < OFF_WEDGE_T) { p = bout;  off = i - OFF_BOUT; }
    else if (i < OFF_WFRAG) { // transposed W_edge: wt[col*64+k] = W_edge[k*128+col]
        int idx = i - OFF_WEDGE_T;
        int col = idx >> 6, k = idx & 63;
        w[i] = loadin(Wedge, (long)k * OUT_DIM + col, f);
        return;
    } else if (i < OFF_WFG) {
        // W_edge fragments: wdx = mt*512 + tt*256 + l*4 + s/2 (k in 0..63)
        int wdx = i - OFF_WFRAG;
        int sp = (wdx & 3) * 2;
        int l = (wdx >> 2) & 63;
        int tt = (wdx >> 8) & 1;
        int mt = wdx >> 9;
        int k0 = tt * 32 + ((l >> 4) << 3);
        int col = mt * 16 + (l & 15);
        float v0 = loadin(Wedge, (long)(k0 + sp) * OUT_DIM + col, f);
        float v1 = loadin(Wedge, (long)(k0 + sp + 1) * OUT_DIM + col, f);
        *(u32*)&w[i] = (u32)f2b_bits(v0) | ((u32)f2b_bits(v1) << 16);
        return;
    } else if (i < OFF_WFO_HI) {
        // W_gate fragments: wdx = ct*2048 + tt*256 + l*4 + s/2 (k in 0..255)
        int wdx = i - OFF_WFG;
        int sp = (wdx & 3) * 2;
        int l = (wdx >> 2) & 63;
        int tt = (wdx >> 8) & 7;
        int ct = wdx >> 11;
        int k0 = tt * 32 + ((l >> 4) << 3);
        int c = ct * 16 + (l & 15);
        float v0 = loadin(Wgate, (long)(k0 + sp) * OUT_DIM + c, f);
        float v1 = loadin(Wgate, (long)(k0 + sp + 1) * OUT_DIM + c, f);
        *(u32*)&w[i] = (u32)f2b_bits(v0) | ((u32)f2b_bits(v1) << 16);
        return;
    } else {
        // 128-k matrices (W_out/W_src/W_dst, hi or lo): wdx = ct*1024 + tt*256 + l*4 + s/2
        const void* M; int base; int wantlo;
        if (i < OFF_WFO_LO)      { M = Wout; base = OFF_WFO_HI; wantlo = 0; }
        else if (i < OFF_WFS_HI) { M = Wout; base = OFF_WFO_LO; wantlo = 1; }
        else if (i < OFF_WFS_LO) { M = Wsrc; base = OFF_WFS_HI; wantlo = 0; }
        else if (i < OFF_WFD_HI) { M = Wsrc; base = OFF_WFS_LO; wantlo = 1; }
        else if (i < OFF_WFD_LO) { M = Wdst; base = OFF_WFD_HI; wantlo = 0; }
        else                     { M = Wdst; base = OFF_WFD_LO; wantlo = 1; }
        int wdx = i - base;
        int sp = (wdx & 3) * 2;
        int l = (wdx >> 2) & 63;
        int tt = (wdx >> 8) & 3;
        int ct = wdx >> 10;
        int k0 = tt * 32 + ((l >> 4) << 3);
        int c = ct * 16 + (l & 15);
        float v0 = loadin(M, (long)(k0 + sp) * OUT_DIM + c, f);
        float v1 = loadin(M, (long)(k0 + sp + 1) * OUT_DIM + c, f);
        if (wantlo) {
            v0 = v0 - b2f_raw(f2b_bits(v0));
            v1 = v1 - b2f_raw(f2b_bits(v1));
        }
        *(u32*)&w[i] = (u32)f2b_bits(v0) | ((u32)f2b_bits(v1) << 16);
        return;
    }
    w[i] = loadin(p, off, f);
}

// ---------- exclusive prefix sum: thread-coarsened, 22 barriers total ----------
#define SCAN_CHUNK 49   // 49*1024 = 50176 >= N_NODES
__global__ __launch_bounds__(1024) void k_scan(const int* __restrict__ deg,
                                               int* __restrict__ rowptr) {
    __shared__ int part[1024];
    int tid = threadIdx.x;
    int base = tid * SCAN_CHUNK;
    int s = 0;
    for (int j = 0; j < SCAN_CHUNK; j++) {
        int i = base + j;
        if (i < N_NODES) s += deg[i];
    }
    part[tid] = s;
    __syncthreads();
    for (int st = 1; st < 1024; st <<= 1) {
        int v = (tid >= st) ? part[tid - st] : 0;
        __syncthreads();
        part[tid] += v;
        __syncthreads();
    }
    int run = (tid == 0) ? 0 : part[tid - 1];
    for (int j = 0; j < SCAN_CHUNK; j++) {
        int i = base + j;
        if (i < N_NODES) {
            rowptr[i] = run;
            run += deg[i];
        }
    }
    if (N_NODES >= base && N_NODES < base + SCAN_CHUNK) rowptr[N_NODES] = run;
}

// ---------- fused: node projections on MFMA (blocks 0..781) || edge permute ----------
#define PROJ_PAD 134
__global__ __launch_bounds__(256, 4) void k_pp(const void* __restrict__ node,
                                              const float* __restrict__ w, const int* __restrict__ flag,
                                              bf16* __restrict__ f_src, bf16* __restrict__ f_dst,
                                              const int* __restrict__ dst,
                                              const int* __restrict__ rowptr,
                                              const int* __restrict__ rank,
                                              int* __restrict__ perm) {
    if (blockIdx.x >= PROJ_BLOCKS) {
        int e = (blockIdx.x - PROJ_BLOCKS) * 256 + threadIdx.x;
        if (e < N_EDGES) perm[rowptr[dst[e]] + rank[e]] = e;
        return;
    }
    __shared__ float s_t[4][16][PROJ_PAD];
    const int wv = threadIdx.x >> 6;
    const int lane = threadIdx.x & 63;
    const int g = lane >> 4, j16 = lane & 15;
    const int isbf = flag[0];
    const long row0 = (long)blockIdx.x * 64 + wv * 16;
    if (row0 >= N_NODES) return;
    float (*t32)[PROJ_PAD] = s_t[wv];
    long jr = row0 + j16; if (jr >= N_NODES) jr = N_NODES - 1;

    uint4 ah[4], al[4];
    if (isbf) {
        const uint4* np = (const uint4*)node;
#pragma unroll
        for (int tt = 0; tt < 4; tt++) ah[tt] = np[jr * 16 + tt * 4 + g];
    } else {
        const float4* np = (const float4*)node;
#pragma unroll
        for (int tt = 0; tt < 4; tt++) {
            float4 x0 = np[jr * 32 + tt * 8 + g * 2];
            float4 x1 = np[jr * 32 + tt * 8 + g * 2 + 1];
            float xv[8] = {x0.x, x0.y, x0.z, x0.w, x1.x, x1.y, x1.z, x1.w};
            u32 hw[4], lw[4];
#pragma unroll
            for (int s2 = 0; s2 < 4; s2++) {
                u16 h0 = f2b_bits(xv[s2 * 2]), h1 = f2b_bits(xv[s2 * 2 + 1]);
                float r0 = xv[s2 * 2] - b2f_raw(h0);
                float r1 = xv[s2 * 2 + 1] - b2f_raw(h1);
                hw[s2] = (u32)h0 | ((u32)h1 << 16);
                lw[s2] = (u32)f2b_bits(r0) | ((u32)f2b_bits(r1) << 16);
            }
            ah[tt] = make_uint4(hw[0], hw[1], hw[2], hw[3]);
            al[tt] = make_uint4(lw[0], lw[1], lw[2], lw[3]);
        }
    }

    const bf16x8* wsh = (const bf16x8*)(w + OFF_WFS_HI);
    const bf16x8* wsl = (const bf16x8*)(w + OFF_WFS_LO);
    const bf16x8* wdh = (const bf16x8*)(w + OFF_WFD_HI);
    const bf16x8* wdl = (const bf16x8*)(w + OFF_WFD_LO);

    // ---- f_src = x @ W_src + b ----
#pragma unroll
    for (int ct = 0; ct < 8; ct++) {
        float bs = w[OFF_BSRC + ct * 16 + j16];
        f32x4 c = {bs, bs, bs, bs};
#pragma unroll
        for (int tt = 0; tt < 4; tt++) {
            bf16x8 a = *reinterpret_cast<bf16x8*>(&ah[tt]);
            c = __builtin_amdgcn_mfma_f32_16x16x32_bf16(a, wsh[(ct * 4 + tt) * 64 + lane], c, 0, 0, 0);
            c = __builtin_amdgcn_mfma_f32_16x16x32_bf16(a, wsl[(ct * 4 + tt) * 64 + lane], c, 0, 0, 0);
        }
        if (!isbf) {
#pragma unroll
            for (int tt = 0; tt < 4; tt++)
                c = __builtin_amdgcn_mfma_f32_16x16x32_bf16(*reinterpret_cast<bf16x8*>(&al[tt]),
                                                            wsh[(ct * 4 + tt) * 64 + lane], c, 0, 0, 0);
        }
#pragma unroll
        for (int r = 0; r < 4; r++) t32[g * 4 + r][ct * 16 + j16] = c[r];
    }
    for (int it = 0; it < 16; it++) {
        long rr = row0 + it;
        if (rr >= N_NODES) break;
        ((u32*)f_src)[rr * 64 + lane] =
            (u32)f2b_bits(t32[it][lane * 2]) | ((u32)f2b_bits(t32[it][lane * 2 + 1]) << 16);
    }

    // ---- f_dst = x @ W_dst + b ----
#pragma unroll
    for (int ct = 0; ct < 8; ct++) {
        float bd = w[OFF_BDST + ct * 16 + j16];
        f32x4 c = {bd, bd, bd, bd};
#pragma unroll
        for (int tt = 0; tt < 4; tt++) {
            bf16x8 a = *reinterpret_cast<bf16x8*>(&ah[tt]);
            c = __builtin_amdgcn_mfma_f32_16x16x32_bf16(a, wdh[(ct * 4 + tt) * 64 + lane], c, 0, 0, 0);
            c = __builtin_amdgcn_mfma_f32_16x16x32_bf16(a, wdl[(ct * 4 + tt) * 64 + lane], c, 0, 0, 0);
        }
        if (!isbf) {
#pragma unroll
            for (int tt = 0; tt < 4; tt++)
                c = __builtin_amdgcn_mfma_f32_16x16x32_bf16(*reinterpret_cast<bf16x8*>(&al[tt]),
                                                            wdh[(ct * 4 + tt) * 64 + lane], c, 0, 0, 0);
        }
#pragma unroll
        for (int r = 0; r < 4; r++) t32[g * 4 + r][ct * 16 + j16] = c[r];
    }
    for (int it = 0; it < 16; it++) {
        long rr = row0 + it;
        if (rr >= N_NODES) break;
        ((u32*)f_dst)[rr * 64 + lane] =
            (u32)f2b_bits(t32[it][lane * 2]) | ((u32)f2b_bits(t32[it][lane * 2 + 1]) << 16);
    }
}

// ---------- per-node aggregation: wave-per-node, fused logits+softmax+agg ----------
// All LDS wave-private -> zero barriers. Single dispatch.
// R14: tile-0 edge_feat prefetch (8 VGPR, short live range across Phase 2+3a).
#define CAPR 24   // cached f_src rows per node (P(deg>24)~2% re-gathers L2-warm)
__global__ __launch_bounds__(256, 4) void k_node_agg(const int* __restrict__ rowptr,
                                                  const int* __restrict__ perm,
                                                  const int* __restrict__ src,
                                                  const bf16* __restrict__ f_src,
                                                  const bf16* __restrict__ f_dst,
                                                  const void* __restrict__ edge_feat,
                                                  const float* __restrict__ w, const int* __restrict__ flag,
                                                  bf16* __restrict__ h_node, bf16* __restrict__ edge_max,
                                                  bf16* __restrict__ out_a_b, float* __restrict__ out_a_f) {
    __shared__ int s_esrc[4][64];
    __shared__ __align__(16) float s_a[4][64][4];
    __shared__ __align__(16) float s_vmax[4][128];
    __shared__ u32 s_xs[4][CAPR][64];   // cached f_src rows (u32 = 2 bf16 cols/lane)

    const int wv = threadIdx.x >> 6;
    const int lane = threadIdx.x & 63;
    const int n = blockIdx.x * 4 + wv;
    const int isbf = flag[0];
    const int r0 = rowptr[n], r1 = rowptr[n + 1];
    const int deg = r1 - r0;

    int* esrc = s_esrc[wv];
    float (*aA)[4] = s_a[wv];
    float* vm = s_vmax[wv];
    u32 (*xs)[64] = s_xs[wv];

    const u32* fs32 = (const u32*)f_src;
    const int g = lane >> 4;          // head group of this lane's column pair
    const int dm = deg < 64 ? deg : 64;

    // ---- Phase 1: per-lane edge metadata ----
    int e0 = 0, sv = 0;
    if (lane < deg) {
        e0 = perm[r0 + lane];
        sv = src[e0];
        esrc[lane] = sv;
    }

    // ---- Phase L: fused GATv2 logits (+ row cache fill), 8 gathers in flight ----
    u32 fdw = ((const u32*)f_dst)[(long)n * 64 + lane];
    const float fdlo = lo16(fdw), fdhi = hi16(fdw);
    const float2 awc = *(const float2*)&w[OFF_ATTN + lane * 2];
    {
        int j = 0;
        for (; j + 8 <= dm; j += 8) {
            int sA = __shfl(sv, j),     sB = __shfl(sv, j + 1);
            int sC = __shfl(sv, j + 2), sD = __shfl(sv, j + 3);
            int sE = __shfl(sv, j + 4), sF = __shfl(sv, j + 5);
            int sG = __shfl(sv, j + 6), sH = __shfl(sv, j + 7);
            u32 vA = fs32[(long)sA * 64 + lane];
            u32 vB = fs32[(long)sB * 64 + lane];
            u32 vC = fs32[(long)sC * 64 + lane];
            u32 vD = fs32[(long)sD * 64 + lane];
            u32 vE = fs32[(long)sE * 64 + lane];
            u32 vF = fs32[(long)sF * 64 + lane];
            u32 vG = fs32[(long)sG * 64 + lane];
            u32 vH = fs32[(long)sH * 64 + lane];
            if (j + 7 < CAPR) {   // CAPR multiple of 8
                xs[j][lane] = vA;     xs[j + 1][lane] = vB;
                xs[j + 2][lane] = vC; xs[j + 3][lane] = vD;
                xs[j + 4][lane] = vE; xs[j + 5][lane] = vF;
                xs[j + 6][lane] = vG; xs[j + 7][lane] = vH;
            }
            float rA = red16(logit_part(vA, fdlo, fdhi, awc));
            float rB = red16(logit_part(vB, fdlo, fdhi, awc));
            float rC = red16(logit_part(vC, fdlo, fdhi, awc));
            float rD = red16(logit_part(vD, fdlo, fdhi, awc));
            float rE = red16(logit_part(vE, fdlo, fdhi, awc));
            float rF = red16(logit_part(vF, fdlo, fdhi, awc));
            float rG = red16(logit_part(vG, fdlo, fdhi, awc));
            float rH = red16(logit_part(vH, fdlo, fdhi, awc));
            if ((lane & 15) == 0) {
                aA[j][g] = rA;     aA[j + 1][g] = rB;
                aA[j + 2][g] = rC; aA[j + 3][g] = rD;
                aA[j + 4][g] = rE; aA[j + 5][g] = rF;
                aA[j + 6][g] = rG; aA[j + 7][g] = rH;
            }
        }
        for (; j + 4 <= dm; j += 4) {
            int sA = __shfl(sv, j), sB = __shfl(sv, j + 1);
            int sC = __shfl(sv, j + 2), sD = __shfl(sv, j + 3);
            u32 vA = fs32[(long)sA * 64 + lane];
            u32 vB = fs32[(long)sB * 64 + lane];
            u32 vC = fs32[(long)sC * 64 + lane];
            u32 vD = fs32[(long)sD * 64 + lane];
            if (j + 3 < CAPR) {
                xs[j][lane] = vA; xs[j + 1][lane] = vB;
                xs[j + 2][lane] = vC; xs[j + 3][lane] = vD;
            }
            float rA = red16(logit_part(vA, fdlo, fdhi, awc));
            float rB = red16(logit_part(vB, fdlo, fdhi, awc));
            float rC = red16(logit_part(vC, fdlo, fdhi, awc));
            float rD = red16(logit_part(vD, fdlo, fdhi, awc));
            if ((lane & 15) == 0) {
                aA[j][g] = rA; aA[j + 1][g] = rB;
                aA[j + 2][g] = rC; aA[j + 3][g] = rD;
            }
        }
        for (; j < dm; j++) {
            int sA = __shfl(sv, j);
            u32 vA = fs32[(long)sA * 64 + lane];
            if (j < CAPR) xs[j][lane] = vA;
            float rA = red16(logit_part(vA, fdlo, fdhi, awc));
            if ((lane & 15) == 0) aA[j][g] = rA;
        }
    }

    // ---- Phase P0: tile-0 edge_feat prefetch (short live range: Phase 2+3a) ----
    bf16x8 pb0, pb1;
    if (isbf && deg > 0) {
        int ej0 = __shfl(e0, lane & 15);
        const uint4* ef4 = (const uint4*)edge_feat;
        uint4 q0 = ef4[(long)ej0 * 8 + g];
        uint4 q1 = ef4[(long)ej0 * 8 + 4 + g];
        pb0 = *reinterpret_cast<bf16x8*>(&q0);
        pb1 = *reinterpret_cast<bf16x8*>(&q1);
    }

    // ---- Phase 2: softmax in registers (lane j owns edge j) ----
    float l0 = -3.0e38f, l1 = -3.0e38f, l2 = -3.0e38f, l3 = -3.0e38f;
    if (lane < deg) {
        float4 lv = *(float4*)aA[lane];
        l0 = lv.x; l1 = lv.y; l2 = lv.z; l3 = lv.w;
    }
    float m0 = l0, m1 = l1, m2 = l2, m3 = l3;
#pragma unroll
    for (int s = 1; s < 64; s <<= 1) {
        m0 = fmaxf(m0, __shfl_xor(m0, s));
        m1 = fmaxf(m1, __shfl_xor(m1, s));
        m2 = fmaxf(m2, __shfl_xor(m2, s));
        m3 = fmaxf(m3, __shfl_xor(m3, s));
    }
    for (int jj = 64; jj < deg; jj++) {   // cold: deg > 64 — cooperative logit, max
        int e = perm[r0 + jj];
        int s0 = src[e];
        u32 v = fs32[(long)s0 * 64 + lane];
        float red = red16(logit_part(v, fdlo, fdhi, awc));
        float q0 = __shfl(red, 0), q1 = __shfl(red, 16);
        float q2 = __shfl(red, 32), q3 = __shfl(red, 48);
        m0 = fmaxf(m0, q0); m1 = fmaxf(m1, q1);
        m2 = fmaxf(m2, q2); m3 = fmaxf(m3, q3);
    }
    float p0 = 0.f, p1 = 0.f, p2 = 0.f, p3 = 0.f;
    if (lane < deg) {
        p0 = __expf(l0 - m0); p1 = __expf(l1 - m1);
        p2 = __expf(l2 - m2); p3 = __expf(l3 - m3);
    }
    float t0 = p0, t1 = p1, t2 = p2, t3 = p3;
#pragma unroll
    for (int s = 1; s < 64; s <<= 1) {
        t0 += __shfl_xor(t0, s);
        t1 += __shfl_xor(t1, s);
        t2 += __shfl_xor(t2, s);
        t3 += __shfl_xor(t3, s);
    }
    for (int jj = 64; jj < deg; jj++) {   // cold: sum of overflow exps (uniform)
        int e = perm[r0 + jj];
        int s0 = src[e];
        u32 v = fs32[(long)s0 * 64 + lane];
        float red = red16(logit_part(v, fdlo, fdhi, awc));
        t0 += __expf(__shfl(red, 0) - m0);
        t1 += __expf(__shfl(red, 16) - m1);
        t2 += __expf(__shfl(red, 32) - m2);
        t3 += __expf(__shfl(red, 48) - m3);
    }
    const float i0 = 1.f / fmaxf(t0, 1e-9f);
    const float i1 = 1.f / fmaxf(t1, 1e-9f);
    const float i2 = 1.f / fmaxf(t2, 1e-9f);
    const float i3 = 1.f / fmaxf(t3, 1e-9f);
    if (lane < deg) {
        float a0 = p0 * i0, a1 = p1 * i1, a2 = p2 * i2, a3 = p3 * i3;
        *(float4*)aA[lane] = make_float4(a0, a1, a2, a3);
        if (isbf) {
            u64 pk = (u64)f2b_bits(a0) | ((u64)f2b_bits(a1) << 16)
                   | ((u64)f2b_bits(a2) << 32) | ((u64)f2b_bits(a3) << 48);
            ((u64*)out_a_b)[e0] = pk;
        } else {
            ((float4*)out_a_f)[e0] = make_float4(a0, a1, a2, a3);
        }
    }

    // ---- Phase 3a: message accumulate — cached rows from LDS, rest from global ----
    const int hsel = g;
    float acc0 = 0.f, acc1 = 0.f;
    const int capn = dm < CAPR ? dm : CAPR;
    int j = 0;
    for (; j + 4 <= capn; j += 4) {
        float a0 = aA[j][hsel], a1 = aA[j + 1][hsel];
        float a2 = aA[j + 2][hsel], a3 = aA[j + 3][hsel];
        u32 v0 = xs[j][lane];
        u32 v1 = xs[j + 1][lane];
        u32 v2 = xs[j + 2][lane];
        u32 v3 = xs[j + 3][lane];
        acc0 += lo16(v0) * a0 + lo16(v1) * a1 + lo16(v2) * a2 + lo16(v3) * a3;
        acc1 += hi16(v0) * a0 + hi16(v1) * a1 + hi16(v2) * a2 + hi16(v3) * a3;
    }
    for (; j < capn; j++) {
        float a0 = aA[j][hsel];
        u32 v0 = xs[j][lane];
        acc0 += lo16(v0) * a0;
        acc1 += hi16(v0) * a0;
    }
    for (; j < dm; j++) {   // deg in (CAPR,64]: re-gather (L2-warm)
        int s0 = esrc[j];
        float a0 = aA[j][hsel];
        u32 v0 = fs32[(long)s0 * 64 + lane];
        acc0 += lo16(v0) * a0;
        acc1 += hi16(v0) * a0;
    }
    if (deg > 64) {   // cold: cooperative logit -> a -> out_a + message
        float mh = (hsel & 2) ? ((hsel & 1) ? m3 : m2) : ((hsel & 1) ? m1 : m0);
        float ih = (hsel & 2) ? ((hsel & 1) ? i3 : i2) : ((hsel & 1) ? i1 : i0);
        for (int jj = 64; jj < deg; jj++) {
            int e = perm[r0 + jj];
            int s0 = src[e];
            u32 v = fs32[(long)s0 * 64 + lane];
            float red = red16(logit_part(v, fdlo, fdhi, awc));
            float q0 = __shfl(red, 0), q1 = __shfl(red, 16);
            float q2 = __shfl(red, 32), q3 = __shfl(red, 48);
            float a0 = __expf(q0 - m0) * i0, a1 = __expf(q1 - m1) * i1;
            float a2 = __expf(q2 - m2) * i2, a3 = __expf(q3 - m3) * i3;
            if (lane == 0) {
                if (isbf) {
                    u64 pk = (u64)f2b_bits(a0) | ((u64)f2b_bits(a1) << 16)
                           | ((u64)f2b_bits(a2) << 32) | ((u64)f2b_bits(a3) << 48);
                    ((u64*)out_a_b)[e] = pk;
                } else {
                    ((float4*)out_a_f)[e] = make_float4(a0, a1, a2, a3);
                }
            }
            float qh = (hsel & 2) ? ((hsel & 1) ? q3 : q2) : ((hsel & 1) ? q1 : q0);
            float ah = __expf(qh - mh) * ih;
            acc0 += lo16(v) * ah;
            acc1 += hi16(v) * ah;
        }
    }
    ((u32*)h_node)[n * 64 + lane] =
        (u32)f2b_bits(acc0) | ((u32)f2b_bits(acc1) << 16);

    // ---- Phase 3b: edge encoder GEMM on MFMA + column max ----
    if (deg == 0) {
        ((u32*)edge_max)[(long)n * 64 + lane] = 0u;
        return;
    }
    {
        const bf16x8* wfb = (const bf16x8*)(w + OFF_WFRAG);
        const int ntiles = deg >= 64 ? 4 : ((deg + 15) >> 4);
        for (int nt = 0; nt < ntiles; nt++) {
            const int je = nt * 16 + (lane & 15);
            bf16x8 bf0, bf1;
            if (isbf) {
                if (nt == 0) {
                    bf0 = pb0;   // prefetched in Phase P0 (short live range)
                    bf1 = pb1;
                } else {
                    const int ej = __shfl(e0, je);
                    const uint4* ef = (const uint4*)edge_feat;
                    uint4 q0 = ef[(long)ej * 8 + g];
                    uint4 q1 = ef[(long)ej * 8 + 4 + g];
                    bf0 = *reinterpret_cast<bf16x8*>(&q0);
                    bf1 = *reinterpret_cast<bf16x8*>(&q1);
                }
            } else {
                const int ej = __shfl(e0, je);
                const float4* ef = (const float4*)edge_feat;
                long base = (long)ej * 16 + g * 2;
                float4 x0 = ef[base], x1 = ef[base + 1];
                float4 y0 = ef[base + 8], y1 = ef[base + 9];
                bf0[0] = (short)f2b_bits(x0.x); bf0[1] = (short)f2b_bits(x0.y);
                bf0[2] = (short)f2b_bits(x0.z); bf0[3] = (short)f2b_bits(x0.w);
                bf0[4] = (short)f2b_bits(x1.x); bf0[5] = (short)f2b_bits(x1.y);
                bf0[6] = (short)f2b_bits(x1.z); bf0[7] = (short)f2b_bits(x1.w);
                bf1[0] = (short)f2b_bits(y0.x); bf1[1] = (short)f2b_bits(y0.y);
                bf1[2] = (short)f2b_bits(y0.z); bf1[3] = (short)f2b_bits(y0.w);
                bf1[4] = (short)f2b_bits(y1.x); bf1[5] = (short)f2b_bits(y1.y);
                bf1[6] = (short)f2b_bits(y1.z); bf1[7] = (short)f2b_bits(y1.w);
            }
            const bool valid = je < deg;
#pragma unroll
            for (int mt = 0; mt < 8; mt++) {
                float4 b4 = *(const float4*)(w + OFF_BEDGE + mt * 16 + g * 4);
                f32x4 c = {b4.x, b4.y, b4.z, b4.w};   // bias rides in C-init
                c = __builtin_amdgcn_mfma_f32_16x16x32_bf16(wfb[(mt * 2 + 0) * 64 + lane], bf0, c, 0, 0, 0);
                c = __builtin_amdgcn_mfma_f32_16x16x32_bf16(wfb[(mt * 2 + 1) * 64 + lane], bf1, c, 0, 0, 0);
                float v0 = c[0], v1 = c[1], v2 = c[2], v3 = c[3];
                v0 = v0 > 0.f ? v0 : __expf(v0) - 1.f;
                v1 = v1 > 0.f ? v1 : __expf(v1) - 1.f;
                v2 = v2 > 0.f ? v2 : __expf(v2) - 1.f;
                v3 = v3 > 0.f ? v3 : __expf(v3) - 1.f;
                if (!valid) { v0 = v1 = v2 = v3 = -3.0e38f; }
#pragma unroll
                for (int mm = 1; mm < 16; mm <<= 1) {
                    v0 = fmaxf(v0, __shfl_xor(v0, mm));
                    v1 = fmaxf(v1, __shfl_xor(v1, mm));
                    v2 = fmaxf(v2, __shfl_xor(v2, mm));
                    v3 = fmaxf(v3, __shfl_xor(v3, mm));
                }
                if ((lane & 15) == 0) {
                    float4* vp = (float4*)&vm[mt * 16 + g * 4];
                    if (nt == 0) {
                        *vp = make_float4(v0, v1, v2, v3);
                    } else {
                        float4 o = *vp;
                        *vp = make_float4(fmaxf(o.x, v0), fmaxf(o.y, v1),
                                          fmaxf(o.z, v2), fmaxf(o.w, v3));
                    }
                }
            }
        }
        if (deg > 64) {   // ultra-cold overflow: scalar per-column path
            for (int jj = 64; jj < deg; jj++) {
                long e = perm[r0 + jj];
#pragma unroll 1
                for (int p = 0; p < 2; p++) {
                    int col = lane + p * 64;
                    const float4* wt4 = (const float4*)(w + OFF_WEDGE_T + col * EDGE_DIM);
                    float acc = w[OFF_BEDGE + col];
                    for (int kk = 0; kk < 16; kk++) {
                        float4 wv4 = wt4[kk];
                        float xx, xy, xz, xw;
                        if (isbf) {
                            u64 q = ((const u64*)edge_feat)[e * 16 + kk];
                            xx = b2f_raw((u16)q); xy = b2f_raw((u16)(q >> 16));
                            xz = b2f_raw((u16)(q >> 32)); xw = b2f_raw((u16)(q >> 48));
                        } else {
                            float4 xf = ((const float4*)edge_feat)[e * 16 + kk];
                            xx = xf.x; xy = xf.y; xz = xf.z; xw = xf.w;
                        }
                        acc += xx * wv4.x + xy * wv4.y + xz * wv4.z + xw * wv4.w;
                    }
                    float el = acc > 0.f ? acc : __expf(acc) - 1.f;
                    vm[col] = fmaxf(vm[col], el);
                }
            }
        }
        float2 vv = *(float2*)&vm[lane * 2];
        ((u32*)edge_max)[(long)n * 64 + lane] =
            (u32)f2b_bits(vv.x) | ((u32)f2b_bits(vv.y) << 16);
    }
}

// ---------- fused gate + output projection on MFMA ----------
#define FUSE_PAD 134
__global__ __launch_bounds__(256, 4) void k_fuse(const bf16* __restrict__ h_node,
                                              const bf16* __restrict__ edge_max,
                                              const float* __restrict__ w, const int* __restrict__ flag,
                                              bf16* __restrict__ out_b, float* __restrict__ out_f) {
    __shared__ float s_g[4][16][FUSE_PAD];
    const int wv = threadIdx.x >> 6;
    const int lane = threadIdx.x & 63;
    const int g = lane >> 4, j16 = lane & 15;
    const int isbf = flag[0];
    const long row0 = (long)blockIdx.x * 64 + wv * 16;
    if (row0 >= N_NODES) return;
    float (*g32)[FUSE_PAD] = s_g[wv];

    long jr = row0 + j16; if (jr >= N_NODES) jr = N_NODES - 1;
    uint4 hnf[4], emf[4];
    const uint4* hp = (const uint4*)h_node;
    const uint4* ep = (const uint4*)edge_max;
#pragma unroll
    for (int tt = 0; tt < 4; tt++) {
        hnf[tt] = hp[jr * 16 + tt * 4 + g];
        emf[tt] = ep[jr * 16 + tt * 4 + g];
    }
    const bf16x8* wg = (const bf16x8*)(w + OFF_WFG);
    const bf16x8* wo_hi = (const bf16x8*)(w + OFF_WFO_HI);
    const bf16x8* wo_lo = (const bf16x8*)(w + OFF_WFO_LO);

    // ---- gate GEMM: k=256 (hn: tt0-3, em: tt4-7) -> logits to LDS ----
#pragma unroll
    for (int ct = 0; ct < 8; ct++) {
        float bg = w[OFF_BGATE + ct * 16 + j16];
        f32x4 c = {bg, bg, bg, bg};
#pragma unroll
        for (int tt = 0; tt < 4; tt++)
            c = __builtin_amdgcn_mfma_f32_16x16x32_bf16(*reinterpret_cast<bf16x8*>(&hnf[tt]),
                                                        wg[(ct * 8 + tt) * 64 + lane], c, 0, 0, 0);
#pragma unroll
        for (int tt = 0; tt < 4; tt++)
            c = __builtin_amdgcn_mfma_f32_16x16x32_bf16(*reinterpret_cast<bf16x8*>(&emf[tt]),
                                                        wg[(ct * 8 + 4 + tt) * 64 + lane], c, 0, 0, 0);
#pragma unroll
        for (int r = 0; r < 4; r++) g32[g * 4 + r][ct * 16 + j16] = c[r];
    }

    // ---- fused bf16 A-frags: sigmoid(gate) combined with register hn/em ----
    uint4 ff[4];
#pragma unroll
    for (int tt = 0; tt < 4; tt++) {
        u32 wds[4];
        const float* gr = &g32[j16][tt * 32 + 8 * g];
#pragma unroll
        for (int s2 = 0; s2 < 4; s2++) {
            float glo = gr[s2 * 2], ghi = gr[s2 * 2 + 1];
            u32 hw = ((const u32*)&hnf[tt])[s2];
            u32 ew = ((const u32*)&emf[tt])[s2];
            float slo = 1.f / (1.f + __expf(-glo));
            float shi = 1.f / (1.f + __expf(-ghi));
            float flo = slo * lo16(hw) + (1.f - slo) * lo16(ew);
            float fhi = shi * hi16(hw) + (1.f - shi) * hi16(ew);
            wds[s2] = (u32)f2b_bits(flo) | ((u32)f2b_bits(fhi) << 16);
        }
        ff[tt] = make_uint4(wds[0], wds[1], wds[2], wds[3]);
    }

    // ---- out GEMM: k=128, hi+lo split weights -> D to LDS ----
#pragma unroll
    for (int ct = 0; ct < 8; ct++) {
        float bo = w[OFF_BOUT + ct * 16 + j16];
        f32x4 c = {bo, bo, bo, bo};
#pragma unroll
        for (int tt = 0; tt < 4; tt++) {
            c = __builtin_amdgcn_mfma_f32_16x16x32_bf16(*reinterpret_cast<bf16x8*>(&ff[tt]),
                                                        wo_hi[(ct * 4 + tt) * 64 + lane], c, 0, 0, 0);
            c = __builtin_amdgcn_mfma_f32_16x16x32_bf16(*reinterpret_cast<bf16x8*>(&ff[tt]),
                                                        wo_lo[(ct * 4 + tt) * 64 + lane], c, 0, 0, 0);
        }
#pragma unroll
        for (int r = 0; r < 4; r++) g32[g * 4 + r][ct * 16 + j16] = c[r];
    }

    // ---- coalesced store (row it, lane = col pair) ----
    for (int it = 0; it < 16; it++) {
        long rr = row0 + it;
        if (rr >= N_NODES) break;
        float v0 = g32[it][lane * 2], v1 = g32[it][lane * 2 + 1];
        if (isbf) {
            ((u32*)out_b)[rr * 64 + lane] = (u32)f2b_bits(v0) | ((u32)f2b_bits(v1) << 16);
        } else {
            ((float2*)out_f)[rr * 64 + lane] = make_float2(v0, v1);
        }
    }
}

extern "C" void kernel_launch(void* const* d_in, const int* in_sizes, int n_in,
                              void* d_out, int out_size, void* d_ws, size_t ws_size,
                              hipStream_t stream) {
    const void* node_feat = d_in[0];
    const void* edge_feat = d_in[1];
    const int* src = (const int*)d_in[2];
    const int* dst = (const int*)d_in[3];

    // workspace layout (bytes), total ~52.5 MB (proven-safe < 59.6 MB):
    //   0        .. 12.8M : f_src   bf16 [N][128]
    //   12.8M    .. 25.6M : f_dst   bf16 [N][128]  -> edge_max overlays (same [n] slot,
    //                       read-before-write within the owning wave)
    //   32.0M    .. 44.8M : h_node  bf16 [N][128]
    //   44.8M    ..       : deg, rowptr, perm, wcanon(+frags 675KB), flag, rank
    char* ws = (char*)d_ws;
    bf16* f_src = (bf16*)ws;
    bf16* f_dst = (bf16*)(ws + 12800000);
    bf16* edge_max = (bf16*)(ws + 12800000);  // overlays f_dst; node n's wave reads
                                              // f_dst[n] before writing edge_max[n]
    bf16* h_node = (bf16*)(ws + 32000000);
    int* deg = (int*)(ws + 44800000);
    int* rowptr = (int*)(ws + 45000000);
    int* perm = (int*)(ws + 45400016);
    float* wcanon = (float*)(ws + 48600032);  // 168704 floats -> ends 49274848
    int* flag = (int*)(ws + 49274848);
    int* rank = (int*)(ws + 49280000);        // 3.2MB -> ends 52480000

    bf16* out_b = (bf16*)d_out;
    float* out_f = (float*)d_out;
    bf16* out_a_b = out_b + (size_t)N_NODES * OUT_DIM;
    float* out_a_f = out_f + (size_t)N_NODES * OUT_DIM;

    k_init<<<(N_NODES + 255) / 256, 256, 0, stream>>>(node_feat, flag, deg);
    k_prep<<<WCONV_BLOCKS + HIST_BLOCKS, 256, 0, stream>>>(
        d_in[4], d_in[5], d_in[6], d_in[7], d_in[8], d_in[9], d_in[10],
        d_in[11], d_in[12], d_in[13], d_in[14], wcanon, flag, dst, deg, rank);
    k_scan<<<1, 1024, 0, stream>>>(deg, rowptr);
    k_pp<<<PROJ_BLOCKS + HIST_BLOCKS, 256, 0, stream>>>(node_feat, wcanon, flag, f_src, f_dst,
                                                        dst, rowptr, rank, perm);
    k_node_agg<<<N_NODES / 4, 256, 0, stream>>>(rowptr, perm, src, f_src, f_dst, edge_feat,
                                                wcanon, flag, h_node, edge_max, out_a_b, out_a_f);
    k_fuse<<<(N_NODES + 63) / 64, 256, 0, stream>>>(h_node, edge_max, wcanon, flag, out_b, out_f);
}